// Round 1
// baseline (1588.227 us; speedup 1.0000x reference)
//
#include <hip/hip_runtime.h>

namespace {
constexpr int kB = 2;
constexpr int kH = 12;
constexpr int kD = 64;
constexpr int kC = 768;
constexpr int kF = 8;
constexpr int kP = 196;
constexpr int kS = kF * kP;      // 1568
constexpr int kN = 1 + kS;       // 1569
constexpr int k3C = 3 * kC;      // 2304
constexpr float kScale = 0.125f; // d^-0.5
}

// ---------- generic fp32 GEMM: C[M,N] = A[M,K] @ B[K,N] (+ bias) ----------
// 64x64 tile, K-step 16, 256 threads, 4x4 micro-tile per thread.
// N must be a multiple of 64, K a multiple of 16 (true for all calls here).
__global__ __launch_bounds__(256) void gemm_f32(
    const float* __restrict__ A, const float* __restrict__ B,
    const float* __restrict__ bias, float* __restrict__ Cc,
    int M, int N, int K, int lda, int ldb, int ldc) {
  __shared__ __align__(16) float As[16][65];
  __shared__ __align__(16) float Bs[16][64];
  const int tid = threadIdx.x;
  const int tx = tid & 15, ty = tid >> 4;
  const int mBase = blockIdx.y * 64, nBase = blockIdx.x * 64;
  const int am = tid >> 2;       // 0..63 (A-tile row)
  const int ak = (tid & 3) * 4;  // 0,4,8,12 (A-tile k)
  const int bk = tid >> 4;       // 0..15 (B-tile k)
  const int bn = (tid & 15) * 4; // 0..60 (B-tile col)
  float acc[4][4] = {};
  for (int kt = 0; kt < K; kt += 16) {
    float4 av;
    if (mBase + am < M)
      av = *(const float4*)(A + (size_t)(mBase + am) * lda + kt + ak);
    else
      av = make_float4(0.f, 0.f, 0.f, 0.f);
    float4 bv = *(const float4*)(B + (size_t)(kt + bk) * ldb + nBase + bn);
    As[ak + 0][am] = av.x;
    As[ak + 1][am] = av.y;
    As[ak + 2][am] = av.z;
    As[ak + 3][am] = av.w;
    *(float4*)&Bs[bk][bn] = bv;
    __syncthreads();
#pragma unroll
    for (int kk = 0; kk < 16; ++kk) {
      float a0 = As[kk][ty * 4 + 0], a1 = As[kk][ty * 4 + 1];
      float a2 = As[kk][ty * 4 + 2], a3 = As[kk][ty * 4 + 3];
      float b0 = Bs[kk][tx * 4 + 0], b1 = Bs[kk][tx * 4 + 1];
      float b2 = Bs[kk][tx * 4 + 2], b3 = Bs[kk][tx * 4 + 3];
      acc[0][0] = fmaf(a0, b0, acc[0][0]);
      acc[0][1] = fmaf(a0, b1, acc[0][1]);
      acc[0][2] = fmaf(a0, b2, acc[0][2]);
      acc[0][3] = fmaf(a0, b3, acc[0][3]);
      acc[1][0] = fmaf(a1, b0, acc[1][0]);
      acc[1][1] = fmaf(a1, b1, acc[1][1]);
      acc[1][2] = fmaf(a1, b2, acc[1][2]);
      acc[1][3] = fmaf(a1, b3, acc[1][3]);
      acc[2][0] = fmaf(a2, b0, acc[2][0]);
      acc[2][1] = fmaf(a2, b1, acc[2][1]);
      acc[2][2] = fmaf(a2, b2, acc[2][2]);
      acc[2][3] = fmaf(a2, b3, acc[2][3]);
      acc[3][0] = fmaf(a3, b0, acc[3][0]);
      acc[3][1] = fmaf(a3, b1, acc[3][1]);
      acc[3][2] = fmaf(a3, b2, acc[3][2]);
      acc[3][3] = fmaf(a3, b3, acc[3][3]);
    }
    __syncthreads();
  }
#pragma unroll
  for (int i = 0; i < 4; ++i) {
    int m = mBase + ty * 4 + i;
    if (m < M) {
      float4 o;
      int n0 = nBase + tx * 4;
      o.x = acc[i][0] + (bias ? bias[n0 + 0] : 0.f);
      o.y = acc[i][1] + (bias ? bias[n0 + 1] : 0.f);
      o.z = acc[i][2] + (bias ? bias[n0 + 2] : 0.f);
      o.w = acc[i][3] + (bias ? bias[n0 + 3] : 0.f);
      *(float4*)(Cc + (size_t)m * ldc + n0) = o;
    }
  }
}

// ---------- CLS-token attention: one block per (b,h) ----------
__global__ __launch_bounds__(256) void cls_attn_k(const float* __restrict__ qkv,
                                                  float* __restrict__ xin) {
  __shared__ float logit[kN];
  __shared__ float qs[kD];
  __shared__ float red[8];
  __shared__ float pb[256];
  const int bh = blockIdx.x;
  const int b = bh / kH, h = bh % kH;
  const int tid = threadIdx.x;
  const size_t base = (size_t)b * kN * k3C;
  if (tid < kD) qs[tid] = qkv[base + h * kD + tid] * kScale;
  __syncthreads();
  float lmax = -1e30f;
  for (int n = tid; n < kN; n += 256) {
    const float* kr = qkv + base + (size_t)n * k3C + kC + h * kD;
    float acc = 0.f;
#pragma unroll
    for (int j = 0; j < kD; ++j) acc = fmaf(qs[j], kr[j], acc);
    logit[n] = acc;
    lmax = fmaxf(lmax, acc);
  }
#pragma unroll
  for (int o = 32; o; o >>= 1) lmax = fmaxf(lmax, __shfl_xor(lmax, o));
  if ((tid & 63) == 0) red[tid >> 6] = lmax;
  __syncthreads();
  lmax = fmaxf(fmaxf(red[0], red[1]), fmaxf(red[2], red[3]));
  float lsum = 0.f;
  for (int n = tid; n < kN; n += 256) {
    float p = __expf(logit[n] - lmax);
    logit[n] = p;
    lsum += p;
  }
#pragma unroll
  for (int o = 32; o; o >>= 1) lsum += __shfl_xor(lsum, o);
  if ((tid & 63) == 0) red[4 + (tid >> 6)] = lsum;
  __syncthreads();
  const float inv = 1.f / (red[4] + red[5] + red[6] + red[7]);
  const int j = tid & 63, part = tid >> 6;
  float acc = 0.f;
  for (int n = part; n < kN; n += 4)
    acc = fmaf(logit[n], qkv[base + (size_t)n * k3C + 2 * kC + h * kD + j], acc);
  pb[tid] = acc;
  __syncthreads();
  if (part == 0) {
    float o = (pb[j] + pb[64 + j] + pb[128 + j] + pb[192 + j]) * inv;
    xin[(size_t)(b * kN) * kC + h * kD + j] = o;
  }
}

// ---------- per-frame spatial attention ----------
// grid: (98 q-tiles, 8 frames, 24 bh). Block: 256 threads, TQ=16 queries.
__global__ __launch_bounds__(256) void sp_attn_k(const float* __restrict__ qkv,
                                                 float* __restrict__ x4) {
  __shared__ __align__(16) float KV[kP * 65];  // K padded [n*65+j]; then V flat [n*64+j]
  __shared__ float W[16][197];
  const int tid = threadIdx.x;
  const int qt = blockIdx.x;
  const int f = blockIdx.y;
  const int bh = blockIdx.z;
  const int b = bh / kH, h = bh % kH;
  const int s0 = qt * 16;
  // stage K_f (196 x 64), padded stride 65 for conflict-free column reads
  const float* kbase = qkv + (size_t)(b * kN + 1 + f * kP) * k3C + kC + h * kD;
  for (int e = tid; e < kP * kD; e += 256) {
    int n = e >> 6, j = e & 63;
    KV[n * 65 + j] = kbase[(size_t)n * k3C + j];
  }
  __syncthreads();
  // logits (scaled) into W
  const float* qbase = qkv + (size_t)(b * kN + 1 + s0) * k3C + h * kD;
  for (int e = tid; e < 16 * kP; e += 256) {
    int qq = e / kP, n = e - qq * kP;
    const float* qr = qbase + (size_t)qq * k3C;
    float acc = 0.f;
#pragma unroll
    for (int j = 0; j < kD; ++j) acc = fmaf(qr[j], KV[n * 65 + j], acc);
    W[qq][n] = acc * kScale;
  }
  __syncthreads();
  // stage V_f flat (overwrites K buffer) + softmax rows of W
  const float* vbase = qkv + (size_t)(b * kN + 1 + f * kP) * k3C + 2 * kC + h * kD;
  for (int e = tid; e < kP * kD; e += 256)
    KV[e] = vbase[(size_t)(e >> 6) * k3C + (e & 63)];
  {
    const int r = tid >> 4, g = tid & 15;
    float m = -1e30f;
    for (int n = g; n < kP; n += 16) m = fmaxf(m, W[r][n]);
#pragma unroll
    for (int o = 8; o; o >>= 1) m = fmaxf(m, __shfl_xor(m, o, 16));
    float sum = 0.f;
    for (int n = g; n < kP; n += 16) {
      float p = __expf(W[r][n] - m);
      W[r][n] = p;
      sum += p;
    }
#pragma unroll
    for (int o = 8; o; o >>= 1) sum += __shfl_xor(sum, o, 16);
    const float inv = 1.f / sum;
    for (int n = g; n < kP; n += 16) W[r][n] *= inv;
  }
  __syncthreads();
  // out[q] = W[q,:] @ V
  const int qq = tid >> 4, jg = tid & 15;
  float o0 = 0.f, o1 = 0.f, o2 = 0.f, o3 = 0.f;
  for (int n = 0; n < kP; ++n) {
    float w = W[qq][n];
    float4 v = *(const float4*)&KV[n * 64 + jg * 4];
    o0 = fmaf(w, v.x, o0);
    o1 = fmaf(w, v.y, o1);
    o2 = fmaf(w, v.z, o2);
    o3 = fmaf(w, v.w, o3);
  }
  float4 ov = make_float4(o0, o1, o2, o3);
  size_t off = ((size_t)(b * kS + s0 + qq) * kF + f) * kC + h * kD + jg * 4;
  *(float4*)(x4 + off) = ov;
}

// ---------- xd = diagonal gather: xd[b,s,:] = x4[b,s,s/P,:] ----------
__global__ void xd_gather_k(const float* __restrict__ x4, float* __restrict__ xd) {
  const int idx = blockIdx.x * 256 + threadIdx.x;
  const int total = kB * kS * (kC / 4);
  if (idx >= total) return;
  const int row = idx / (kC / 4);
  const int cg = idx - row * (kC / 4);
  const int b = row / kS, s = row - b * kS;
  const int fq = s / kP;
  ((float4*)xd)[(size_t)row * (kC / 4) + cg] =
      ((const float4*)x4)[((size_t)(b * kS + s) * kF + fq) * (kC / 4) + cg];
}

// ---------- temporal attn over F=8 + weighted sum; 1 wave per (b,h,s) ----------
__global__ __launch_bounds__(256) void attn2_k(
    const float* __restrict__ q2, const float* __restrict__ k2,
    const float* __restrict__ x4, float* __restrict__ xin,
    float* __restrict__ attn2out) {
  const int item = blockIdx.x * 4 + (threadIdx.x >> 6);  // 0..37631
  const int lane = threadIdx.x & 63;
  const int s = item % kS;
  const int t = item / kS;
  const int h = t % kH, b = t / kH;
  const float qv = q2[(size_t)(b * kS + s) * kC + h * kD + lane] * kScale;
  float l[kF];
#pragma unroll
  for (int f = 0; f < kF; ++f) {
    float p = qv * k2[((size_t)(b * kS + s) * kF + f) * kC + h * kD + lane];
#pragma unroll
    for (int o = 32; o; o >>= 1) p += __shfl_xor(p, o);
    l[f] = p;
  }
  float m = l[0];
#pragma unroll
  for (int f = 1; f < kF; ++f) m = fmaxf(m, l[f]);
  float sum = 0.f;
#pragma unroll
  for (int f = 0; f < kF; ++f) {
    l[f] = __expf(l[f] - m);
    sum += l[f];
  }
  const float inv = 1.f / sum;
  float o = 0.f;
#pragma unroll
  for (int f = 0; f < kF; ++f)
    o = fmaf(l[f] * inv,
             x4[((size_t)(b * kS + s) * kF + f) * kC + h * kD + lane], o);
  if (lane < kF)
    attn2out[((size_t)(b * kH + h) * kS + s) * kF + lane] = l[lane] * inv;
  xin[(size_t)(b * kN + 1 + s) * kC + h * kD + lane] = o;
}

extern "C" void kernel_launch(void* const* d_in, const int* in_sizes, int n_in,
                              void* d_out, int out_size, void* d_ws,
                              size_t ws_size, hipStream_t stream) {
  const float* x = (const float*)d_in[0];
  const float* Wqkv = (const float*)d_in[1];
  const float* Wq = (const float*)d_in[2];
  const float* Wkv = (const float*)d_in[3];
  const float* Wproj = (const float*)d_in[4];
  const float* bproj = (const float*)d_in[5];

  float* ws = (float*)d_ws;
  float* qkv = ws;                       // 3138*2304 = 7,229,952
  float* x4 = qkv + (size_t)3138 * 2304; // 25088*768 = 19,267,584
  float* xin = x4 + (size_t)25088 * 768; // 3138*768  =  2,409,984
  float* xd = xin + (size_t)3138 * 768;  // 3136*768  =  2,408,448
  float* q2 = xd + (size_t)3136 * 768;   // 3136*768
  float* k2 = q2 + (size_t)3136 * 768;   // 25088*768 = 19,267,584
  float* out = (float*)d_out;
  float* attn2 = out + (size_t)kB * kN * kC;

  // 1. qkv = x @ Wqkv                         (3138 x 2304 x 768)
  gemm_f32<<<dim3(36, 50), 256, 0, stream>>>(x, Wqkv, nullptr, qkv, 3138, 2304,
                                             768, 768, 2304, 2304);
  // 2. cls attention -> xin row 0 of each batch
  cls_attn_k<<<24, 256, 0, stream>>>(qkv, xin);
  // 3. per-frame spatial attention -> x4 (B,S,F,C)
  sp_attn_k<<<dim3(98, 8, 24), 256, 0, stream>>>(qkv, x4);
  // 4. xd diagonal gather
  xd_gather_k<<<(kB * kS * (kC / 4) + 255) / 256, 256, 0, stream>>>(x4, xd);
  // 5. q2 = xd @ Wq                            (3136 x 768 x 768)
  gemm_f32<<<dim3(12, 49), 256, 0, stream>>>(xd, Wq, nullptr, q2, 3136, 768,
                                             768, 768, 768, 768);
  // 6. k2 = x4 @ Wkv[:, :768]                  (25088 x 768 x 768)
  gemm_f32<<<dim3(12, 392), 256, 0, stream>>>(x4, Wkv, nullptr, k2, 25088, 768,
                                              768, 768, 1536, 768);
  // 7. temporal attention -> xin rows 1.., attn2 -> d_out tail
  attn2_k<<<9408, 256, 0, stream>>>(q2, k2, x4, xin, attn2);
  // 8. out = xin @ Wproj + bproj -> d_out head (3138 x 768 x 768)
  gemm_f32<<<dim3(12, 50), 256, 0, stream>>>(xin, Wproj, bproj, out, 3138, 768,
                                             768, 768, 768, 768);
}

// Round 2
// 1005.927 us; speedup vs baseline: 1.5789x; 1.5789x over previous
//
#include <hip/hip_runtime.h>

namespace {
constexpr int kB = 2;
constexpr int kH = 12;
constexpr int kD = 64;
constexpr int kC = 768;
constexpr int kF = 8;
constexpr int kP = 196;
constexpr int kS = kF * kP;      // 1568
constexpr int kN = 1 + kS;       // 1569
constexpr int k3C = 3 * kC;      // 2304
constexpr float kScale = 0.125f; // d^-0.5
constexpr int kBH = kB * kH;     // 24
constexpr int kPpad = 224;       // keys padded for PV K-dim (7x32)
constexpr int kPstr = 232;       // P LDS row stride (bf16), 16B-aligned, low-conflict
}

typedef __attribute__((ext_vector_type(8))) short bf16x8;
typedef __attribute__((ext_vector_type(4))) float f32x4;

__device__ inline ushort f2bf(float x) {
  union { float f; unsigned u; } v{x};
  unsigned r = v.u + 0x7fff + ((v.u >> 16) & 1);
  return (ushort)(r >> 16);
}

// ---------- generic fp32 GEMM: C[M,N] = A[M,K] @ B[K,N] (+ bias) ----------
__global__ __launch_bounds__(256) void gemm_f32(
    const float* __restrict__ A, const float* __restrict__ B,
    const float* __restrict__ bias, float* __restrict__ Cc,
    int M, int N, int K, int lda, int ldb, int ldc) {
  __shared__ __align__(16) float As[16][65];
  __shared__ __align__(16) float Bs[16][64];
  const int tid = threadIdx.x;
  const int tx = tid & 15, ty = tid >> 4;
  const int mBase = blockIdx.y * 64, nBase = blockIdx.x * 64;
  const int am = tid >> 2;
  const int ak = (tid & 3) * 4;
  const int bk = tid >> 4;
  const int bn = (tid & 15) * 4;
  float acc[4][4] = {};
  for (int kt = 0; kt < K; kt += 16) {
    float4 av;
    if (mBase + am < M)
      av = *(const float4*)(A + (size_t)(mBase + am) * lda + kt + ak);
    else
      av = make_float4(0.f, 0.f, 0.f, 0.f);
    float4 bv = *(const float4*)(B + (size_t)(kt + bk) * ldb + nBase + bn);
    As[ak + 0][am] = av.x;
    As[ak + 1][am] = av.y;
    As[ak + 2][am] = av.z;
    As[ak + 3][am] = av.w;
    *(float4*)&Bs[bk][bn] = bv;
    __syncthreads();
#pragma unroll
    for (int kk = 0; kk < 16; ++kk) {
      float a0 = As[kk][ty * 4 + 0], a1 = As[kk][ty * 4 + 1];
      float a2 = As[kk][ty * 4 + 2], a3 = As[kk][ty * 4 + 3];
      float b0 = Bs[kk][tx * 4 + 0], b1 = Bs[kk][tx * 4 + 1];
      float b2 = Bs[kk][tx * 4 + 2], b3 = Bs[kk][tx * 4 + 3];
      acc[0][0] = fmaf(a0, b0, acc[0][0]);
      acc[0][1] = fmaf(a0, b1, acc[0][1]);
      acc[0][2] = fmaf(a0, b2, acc[0][2]);
      acc[0][3] = fmaf(a0, b3, acc[0][3]);
      acc[1][0] = fmaf(a1, b0, acc[1][0]);
      acc[1][1] = fmaf(a1, b1, acc[1][1]);
      acc[1][2] = fmaf(a1, b2, acc[1][2]);
      acc[1][3] = fmaf(a1, b3, acc[1][3]);
      acc[2][0] = fmaf(a2, b0, acc[2][0]);
      acc[2][1] = fmaf(a2, b1, acc[2][1]);
      acc[2][2] = fmaf(a2, b2, acc[2][2]);
      acc[2][3] = fmaf(a2, b3, acc[2][3]);
      acc[3][0] = fmaf(a3, b0, acc[3][0]);
      acc[3][1] = fmaf(a3, b1, acc[3][1]);
      acc[3][2] = fmaf(a3, b2, acc[3][2]);
      acc[3][3] = fmaf(a3, b3, acc[3][3]);
    }
    __syncthreads();
  }
#pragma unroll
  for (int i = 0; i < 4; ++i) {
    int m = mBase + ty * 4 + i;
    if (m < M) {
      float4 o;
      int n0 = nBase + tx * 4;
      o.x = acc[i][0] + (bias ? bias[n0 + 0] : 0.f);
      o.y = acc[i][1] + (bias ? bias[n0 + 1] : 0.f);
      o.z = acc[i][2] + (bias ? bias[n0 + 2] : 0.f);
      o.w = acc[i][3] + (bias ? bias[n0 + 3] : 0.f);
      *(float4*)(Cc + (size_t)m * ldc + n0) = o;
    }
  }
}

// ---------- pack q,k (scaled q) into bf16 row-major [bh][1568][64] ----------
__global__ void pack_qk_k(const float* __restrict__ qkv, ushort* __restrict__ Qb,
                          ushort* __restrict__ Kb) {
  const int idx = blockIdx.x * 256 + threadIdx.x;
  if (idx >= kBH * kS * kD) return;
  const int j = idx & 63;
  const int s = (idx >> 6) % kS;
  const int bh = idx / (kS * kD);
  const int b = bh / kH, h = bh % kH;
  const size_t src = (size_t)(b * kN + 1 + s) * k3C + h * kD + j;
  Qb[idx] = f2bf(qkv[src] * kScale);
  Kb[idx] = f2bf(qkv[src + kC]);
}

// ---------- pack V transposed: Vt[bh*8+f][64][224] bf16, keys>=196 -> 0 ----------
__global__ void pack_vt_k(const float* __restrict__ qkv, ushort* __restrict__ Vt) {
  const int idx = blockIdx.x * 256 + threadIdx.x;
  if (idx >= kBH * kF * kD * kPpad) return;
  const int n = idx % kPpad;
  const int j = (idx / kPpad) & 63;
  const int f = (idx / (kPpad * kD)) & 7;
  const int bh = idx / (kPpad * kD * kF);
  const int b = bh / kH, h = bh % kH;
  float v = 0.f;
  if (n < kP)
    v = qkv[(size_t)(b * kN + 1 + f * kP + n) * k3C + 2 * kC + h * kD + j];
  Vt[idx] = f2bf(v);
}

// ---------- spatial attention via MFMA ----------
// grid (25, 8, 24); 4 waves/block; wave -> one 16-query M-tile of frame f, head bh.
__global__ __launch_bounds__(256) void sp_attn_mfma(
    const ushort* __restrict__ Qb, const ushort* __restrict__ Kb,
    const ushort* __restrict__ Vt, float* __restrict__ x4) {
  __shared__ __align__(16) ushort Pl[4][16 * kPstr];
  const int w = threadIdx.x >> 6;
  const int lane = threadIdx.x & 63;
  const int mtile = blockIdx.x * 4 + w;
  if (mtile >= 98) return;
  const int f = blockIdx.y;
  const int bh = blockIdx.z;
  const int lr = lane & 15;  // col / row-within-16
  const int lg = lane >> 4;  // 0..3

  // Q fragments (A operand): lane holds Q[m=lr][k=lg*8+j(+32)]
  const ushort* qrow = Qb + ((size_t)bh * kS + mtile * 16 + lr) * kD + lg * 8;
  const bf16x8 a0 = *(const bf16x8*)qrow;
  const bf16x8 a1 = *(const bf16x8*)(qrow + 32);

  // S = Q @ K^T : 13 N-tiles cover 208 >= 196 keys
  f32x4 s[13];
  const ushort* kbase = Kb + ((size_t)bh * kS + f * kP + lr) * kD + lg * 8;
#pragma unroll
  for (int nt = 0; nt < 13; ++nt) {
    const ushort* kr = kbase + (size_t)nt * 16 * kD;
    bf16x8 b0 = *(const bf16x8*)kr;
    bf16x8 b1 = *(const bf16x8*)(kr + 32);
    f32x4 acc = {0.f, 0.f, 0.f, 0.f};
    acc = __builtin_amdgcn_mfma_f32_16x16x32_bf16(a0, b0, acc, 0, 0, 0);
    acc = __builtin_amdgcn_mfma_f32_16x16x32_bf16(a1, b1, acc, 0, 0, 0);
    s[nt] = acc;
  }
  // mask pad keys 196..207 (tile 12, cols lr>=4)
  if (lr >= 4) {
    s[12][0] = -1e30f; s[12][1] = -1e30f; s[12][2] = -1e30f; s[12][3] = -1e30f;
  }

  // softmax per output row (row = lg*4 + r); reduce across the 16 lanes of group lg
#pragma unroll
  for (int r = 0; r < 4; ++r) {
    float m = s[0][r];
#pragma unroll
    for (int nt = 1; nt < 13; ++nt) m = fmaxf(m, s[nt][r]);
#pragma unroll
    for (int o = 8; o; o >>= 1) m = fmaxf(m, __shfl_xor(m, o, 16));
    float sum = 0.f;
#pragma unroll
    for (int nt = 0; nt < 13; ++nt) {
      float p = __expf(s[nt][r] - m);
      s[nt][r] = p;
      sum += p;
    }
#pragma unroll
    for (int o = 8; o; o >>= 1) sum += __shfl_xor(sum, o, 16);
    const float inv = 1.f / sum;
    ushort* row = &Pl[w][(lg * 4 + r) * kPstr];
#pragma unroll
    for (int nt = 0; nt < 13; ++nt) row[nt * 16 + lr] = f2bf(s[nt][r] * inv);
    row[208 + lr] = 0;  // zero pad cols 208..223
  }

  // reload P as A fragments: lane holds P[m=lr][k=lg*8+j+32*kt]
  bf16x8 pa[7];
  const ushort* prow = &Pl[w][lr * kPstr + lg * 8];
#pragma unroll
  for (int kt = 0; kt < 7; ++kt) pa[kt] = *(const bf16x8*)(prow + kt * 32);

  // O = P @ V via Vt (B operand: lane reads Vt[row n=lr+16*nt2][8 consecutive keys])
  const ushort* vbase = Vt + ((size_t)(bh * kF + f) * kD + lr) * kPpad + lg * 8;
  f32x4 o[4];
#pragma unroll
  for (int nt2 = 0; nt2 < 4; ++nt2) {
    f32x4 acc = {0.f, 0.f, 0.f, 0.f};
    const ushort* vb = vbase + (size_t)nt2 * 16 * kPpad;
#pragma unroll
    for (int kt = 0; kt < 7; ++kt) {
      bf16x8 bv = *(const bf16x8*)(vb + kt * 32);
      acc = __builtin_amdgcn_mfma_f32_16x16x32_bf16(pa[kt], bv, acc, 0, 0, 0);
    }
    o[nt2] = acc;
  }

  // write x4[b][s][f][h*64 + c] ; C-layout: col=lr? no: col = lane&15, row=(lane>>4)*4+reg
  const int b = bh / kH, h = bh % kH;
#pragma unroll
  for (int nt2 = 0; nt2 < 4; ++nt2) {
#pragma unroll
    for (int r = 0; r < 4; ++r) {
      const int srow = mtile * 16 + lg * 4 + r;
      x4[(((size_t)(b * kS) + srow) * kF + f) * kC + h * kD + nt2 * 16 + lr] =
          o[nt2][r];
    }
  }
}

// ---------- CLS-token attention: one block per (b,h) ----------
__global__ __launch_bounds__(256) void cls_attn_k(const float* __restrict__ qkv,
                                                  float* __restrict__ xin) {
  __shared__ float logit[kN];
  __shared__ float qs[kD];
  __shared__ float red[8];
  __shared__ float pb[256];
  const int bh = blockIdx.x;
  const int b = bh / kH, h = bh % kH;
  const int tid = threadIdx.x;
  const size_t base = (size_t)b * kN * k3C;
  if (tid < kD) qs[tid] = qkv[base + h * kD + tid] * kScale;
  __syncthreads();
  float lmax = -1e30f;
  for (int n = tid; n < kN; n += 256) {
    const float* kr = qkv + base + (size_t)n * k3C + kC + h * kD;
    float acc = 0.f;
#pragma unroll
    for (int j = 0; j < kD; ++j) acc = fmaf(qs[j], kr[j], acc);
    logit[n] = acc;
    lmax = fmaxf(lmax, acc);
  }
#pragma unroll
  for (int o = 32; o; o >>= 1) lmax = fmaxf(lmax, __shfl_xor(lmax, o));
  if ((tid & 63) == 0) red[tid >> 6] = lmax;
  __syncthreads();
  lmax = fmaxf(fmaxf(red[0], red[1]), fmaxf(red[2], red[3]));
  float lsum = 0.f;
  for (int n = tid; n < kN; n += 256) {
    float p = __expf(logit[n] - lmax);
    logit[n] = p;
    lsum += p;
  }
#pragma unroll
  for (int o = 32; o; o >>= 1) lsum += __shfl_xor(lsum, o);
  if ((tid & 63) == 0) red[4 + (tid >> 6)] = lsum;
  __syncthreads();
  const float inv = 1.f / (red[4] + red[5] + red[6] + red[7]);
  const int j = tid & 63, part = tid >> 6;
  float acc = 0.f;
  for (int n = part; n < kN; n += 4)
    acc = fmaf(logit[n], qkv[base + (size_t)n * k3C + 2 * kC + h * kD + j], acc);
  pb[tid] = acc;
  __syncthreads();
  if (part == 0) {
    float o = (pb[j] + pb[64 + j] + pb[128 + j] + pb[192 + j]) * inv;
    xin[(size_t)(b * kN) * kC + h * kD + j] = o;
  }
}

// ---------- xd = diagonal gather ----------
__global__ void xd_gather_k(const float* __restrict__ x4, float* __restrict__ xd) {
  const int idx = blockIdx.x * 256 + threadIdx.x;
  const int total = kB * kS * (kC / 4);
  if (idx >= total) return;
  const int row = idx / (kC / 4);
  const int cg = idx - row * (kC / 4);
  const int b = row / kS, s = row - b * kS;
  const int fq = s / kP;
  ((float4*)xd)[(size_t)row * (kC / 4) + cg] =
      ((const float4*)x4)[((size_t)(b * kS + s) * kF + fq) * (kC / 4) + cg];
}

// ---------- temporal attn over F=8 ----------
__global__ __launch_bounds__(256) void attn2_k(
    const float* __restrict__ q2, const float* __restrict__ k2,
    const float* __restrict__ x4, float* __restrict__ xin,
    float* __restrict__ attn2out) {
  const int item = blockIdx.x * 4 + (threadIdx.x >> 6);
  const int lane = threadIdx.x & 63;
  const int s = item % kS;
  const int t = item / kS;
  const int h = t % kH, b = t / kH;
  const float qv = q2[(size_t)(b * kS + s) * kC + h * kD + lane] * kScale;
  float l[kF];
#pragma unroll
  for (int f = 0; f < kF; ++f) {
    float p = qv * k2[((size_t)(b * kS + s) * kF + f) * kC + h * kD + lane];
#pragma unroll
    for (int o = 32; o; o >>= 1) p += __shfl_xor(p, o);
    l[f] = p;
  }
  float m = l[0];
#pragma unroll
  for (int f = 1; f < kF; ++f) m = fmaxf(m, l[f]);
  float sum = 0.f;
#pragma unroll
  for (int f = 0; f < kF; ++f) {
    l[f] = __expf(l[f] - m);
    sum += l[f];
  }
  const float inv = 1.f / sum;
  float o = 0.f;
#pragma unroll
  for (int f = 0; f < kF; ++f)
    o = fmaf(l[f] * inv,
             x4[((size_t)(b * kS + s) * kF + f) * kC + h * kD + lane], o);
  if (lane < kF)
    attn2out[((size_t)(b * kH + h) * kS + s) * kF + lane] = l[lane] * inv;
  xin[(size_t)(b * kN + 1 + s) * kC + h * kD + lane] = o;
}

extern "C" void kernel_launch(void* const* d_in, const int* in_sizes, int n_in,
                              void* d_out, int out_size, void* d_ws,
                              size_t ws_size, hipStream_t stream) {
  const float* x = (const float*)d_in[0];
  const float* Wqkv = (const float*)d_in[1];
  const float* Wq = (const float*)d_in[2];
  const float* Wkv = (const float*)d_in[3];
  const float* Wproj = (const float*)d_in[4];
  const float* bproj = (const float*)d_in[5];

  float* ws = (float*)d_ws;
  float* qkv = ws;                       // 3138*2304
  float* x4 = qkv + (size_t)3138 * 2304; // 25088*768
  float* xin = x4 + (size_t)25088 * 768; // 3138*768
  float* xd = xin + (size_t)3138 * 768;  // 3136*768
  float* q2 = xd + (size_t)3136 * 768;   // 3136*768
  float* k2 = q2 + (size_t)3136 * 768;   // 25088*768
  float* out = (float*)d_out;
  float* attn2 = out + (size_t)kB * kN * kC;

  // pack buffers alias the k2 region (k2 is produced only in step 6)
  ushort* Qb = (ushort*)k2;
  ushort* Kb = Qb + (size_t)kBH * kS * kD;
  ushort* Vt = Kb + ((size_t)kBH * kS + 16) * kD;  // +16 pad rows

  // 1. qkv = x @ Wqkv
  gemm_f32<<<dim3(36, 50), 256, 0, stream>>>(x, Wqkv, nullptr, qkv, 3138, 2304,
                                             768, 768, 2304, 2304);
  // 2. pack bf16 operands for spatial attention
  pack_qk_k<<<(kBH * kS * kD + 255) / 256, 256, 0, stream>>>(qkv, Qb, Kb);
  pack_vt_k<<<(kBH * kF * kD * kPpad + 255) / 256, 256, 0, stream>>>(qkv, Vt);
  // 3. cls attention -> xin row 0
  cls_attn_k<<<24, 256, 0, stream>>>(qkv, xin);
  // 4. spatial attention (MFMA) -> x4
  sp_attn_mfma<<<dim3(25, 8, 24), 256, 0, stream>>>(Qb, Kb, Vt, x4);
  // 5. xd diagonal gather
  xd_gather_k<<<(kB * kS * (kC / 4) + 255) / 256, 256, 0, stream>>>(x4, xd);
  // 6. q2 = xd @ Wq
  gemm_f32<<<dim3(12, 49), 256, 0, stream>>>(xd, Wq, nullptr, q2, 3136, 768,
                                             768, 768, 768, 768);
  // 7. k2 = x4 @ Wkv[:, :768]   (overwrites pack buffers — safe, stream-ordered)
  gemm_f32<<<dim3(12, 392), 256, 0, stream>>>(x4, Wkv, nullptr, k2, 25088, 768,
                                              768, 768, 1536, 768);
  // 8. temporal attention
  attn2_k<<<9408, 256, 0, stream>>>(q2, k2, x4, xin, attn2);
  // 9. out = xin @ Wproj + bproj
  gemm_f32<<<dim3(12, 50), 256, 0, stream>>>(xin, Wproj, bproj, out, 3138, 768,
                                             768, 768, 768, 768);
}

// Round 3
// 415.077 us; speedup vs baseline: 3.8263x; 2.4235x over previous
//
#include <hip/hip_runtime.h>

namespace {
constexpr int kB = 2;
constexpr int kH = 12;
constexpr int kD = 64;
constexpr int kC = 768;
constexpr int kF = 8;
constexpr int kP = 196;
constexpr int kS = kF * kP;      // 1568
constexpr int kN = 1 + kS;       // 1569
constexpr int k3C = 3 * kC;      // 2304
constexpr float kScale = 0.125f; // d^-0.5
constexpr int kBH = kB * kH;     // 24
constexpr int kPpad = 224;       // keys padded for PV K-dim (7x32)
constexpr int kPstr = 232;       // P LDS row stride (bf16)
}

typedef __attribute__((ext_vector_type(8))) short bf16x8;
typedef __attribute__((ext_vector_type(4))) float f32x4;

__device__ inline ushort f2bf(float x) {
  union { float f; unsigned u; } v{x};
  unsigned r = v.u + 0x7fff + ((v.u >> 16) & 1);
  return (ushort)(r >> 16);
}
__device__ inline float bf2f(ushort u) {
  union { unsigned u; float f; } v{(unsigned)u << 16};
  return v.f;
}

__device__ __forceinline__ void gload_lds16(const void* g, void* l) {
  __builtin_amdgcn_global_load_lds(
      (const __attribute__((address_space(1))) unsigned int*)g,
      (__attribute__((address_space(3))) unsigned int*)l, 16, 0, 0);
}

// ---------- bf16 MFMA GEMM: C[M,N]f32 = A[M,K]bf16 @ Bt[N,K]bf16^T (+bias) ----
// 128x128 tile, BK=32, 256 threads (4 waves 2x2). K must be mult of 32, N of 128.
__global__ __launch_bounds__(256) void gemm_bf16(
    const ushort* __restrict__ A, const ushort* __restrict__ Bt,
    const float* __restrict__ bias, float* __restrict__ C,
    int M, int N, int K) {
  __shared__ __align__(16) ushort As[128 * 32];
  __shared__ __align__(16) ushort Bs[128 * 32];
  const int tid = threadIdx.x;
  const int m0 = blockIdx.y * 128, n0 = blockIdx.x * 128;
  // staging: thread t stages 16B chunks e=t and e=t+256 for each of A,B.
  // chunk e -> LDS bytes [16e,16e+16) = row r=e/4, chunk c=e%4 of [128][32] tile.
  // source col pre-swizzled: sc = (c ^ ((r>>1)&3))*8   (involution, rule #21)
  const int r0 = tid >> 2, c0 = tid & 3;
  const int r1 = r0 + 64;
  const int sc0 = (c0 ^ ((r0 >> 1) & 3)) * 8;
  const int sc1 = (c0 ^ ((r1 >> 1) & 3)) * 8;
  const int ar0 = min(m0 + r0, M - 1), ar1 = min(m0 + r1, M - 1);
  const ushort* ga0 = A + (size_t)ar0 * K + sc0;
  const ushort* ga1 = A + (size_t)ar1 * K + sc1;
  const ushort* gb0 = Bt + (size_t)(n0 + r0) * K + sc0;
  const ushort* gb1 = Bt + (size_t)(n0 + r1) * K + sc1;
  const int w = tid >> 6;
  char* lA0 = (char*)As + w * 1024;
  char* lA1 = (char*)As + 4096 + w * 1024;
  char* lB0 = (char*)Bs + w * 1024;
  char* lB1 = (char*)Bs + 4096 + w * 1024;
  const int lane = tid & 63;
  const int lr = lane & 15, lg = lane >> 4;
  const int wr = w >> 1, wc = w & 1;
  f32x4 acc[4][4] = {};
  for (int kt = 0; kt < K; kt += 32) {
    gload_lds16(ga0 + kt, lA0);
    gload_lds16(ga1 + kt, lA1);
    gload_lds16(gb0 + kt, lB0);
    gload_lds16(gb1 + kt, lB1);
    __syncthreads();
    bf16x8 af[4], bfr[4];
#pragma unroll
    for (int m = 0; m < 4; ++m) {
      int row = wr * 64 + m * 16 + lr;
      int ch = lg ^ ((row >> 1) & 3);
      af[m] = *(const bf16x8*)(As + row * 32 + ch * 8);
    }
#pragma unroll
    for (int n = 0; n < 4; ++n) {
      int row = wc * 64 + n * 16 + lr;
      int ch = lg ^ ((row >> 1) & 3);
      bfr[n] = *(const bf16x8*)(Bs + row * 32 + ch * 8);
    }
#pragma unroll
    for (int m = 0; m < 4; ++m)
#pragma unroll
      for (int n = 0; n < 4; ++n)
        acc[m][n] =
            __builtin_amdgcn_mfma_f32_16x16x32_bf16(af[m], bfr[n], acc[m][n], 0, 0, 0);
    __syncthreads();
  }
#pragma unroll
  for (int m = 0; m < 4; ++m) {
#pragma unroll
    for (int r = 0; r < 4; ++r) {
      const int mg = m0 + wr * 64 + m * 16 + lg * 4 + r;
      if (mg < M) {
        float* crow = C + (size_t)mg * N + n0 + wc * 64 + lr;
#pragma unroll
        for (int n = 0; n < 4; ++n) {
          float v = acc[m][n][r];
          if (bias) v += bias[n0 + wc * 64 + n * 16 + lr];
          crow[n * 16] = v;
        }
      }
    }
  }
}

// ---------- pack x -> bf16 ----------
__global__ void pack_x_k(const float* __restrict__ X, ushort* __restrict__ Xb,
                         int n4) {
  const int i = blockIdx.x * 256 + threadIdx.x;
  if (i >= n4) return;
  float4 v = ((const float4*)X)[i];
  ushort4 o = {f2bf(v.x), f2bf(v.y), f2bf(v.z), f2bf(v.w)};
  ((ushort4*)Xb)[i] = o;
}

// ---------- pack W[768][ldw] cols[0,Ncols) -> Wt[Ncols][768] bf16 ----------
__global__ __launch_bounds__(256) void pack_wt_k(const float* __restrict__ W,
                                                 ushort* __restrict__ Wt,
                                                 int ldw) {
  __shared__ float t[32][33];
  const int nb = blockIdx.x * 32;
  const int kb = blockIdx.y * 32;
  const int tx = threadIdx.x & 31, ty = threadIdx.x >> 5;
#pragma unroll
  for (int i = 0; i < 32; i += 8)
    t[ty + i][tx] = W[(size_t)(kb + ty + i) * ldw + nb + tx];
  __syncthreads();
#pragma unroll
  for (int i = 0; i < 32; i += 8)
    Wt[(size_t)(nb + ty + i) * 768 + kb + tx] = f2bf(t[tx][ty + i]);
}

// ---------- pack q,k (scaled q) into bf16 row-major [bh][1568][64] ----------
__global__ void pack_qk_k(const float* __restrict__ qkv, ushort* __restrict__ Qb,
                          ushort* __restrict__ Kb) {
  const int idx = blockIdx.x * 256 + threadIdx.x;
  if (idx >= kBH * kS * kD) return;
  const int j = idx & 63;
  const int s = (idx >> 6) % kS;
  const int bh = idx / (kS * kD);
  const int b = bh / kH, h = bh % kH;
  const size_t src = (size_t)(b * kN + 1 + s) * k3C + h * kD + j;
  Qb[idx] = f2bf(qkv[src] * kScale);
  Kb[idx] = f2bf(qkv[src + kC]);
}

// ---------- pack V transposed: Vt[bh*8+f][64][224] bf16 ----------
__global__ void pack_vt_k(const float* __restrict__ qkv, ushort* __restrict__ Vt) {
  const int idx = blockIdx.x * 256 + threadIdx.x;
  if (idx >= kBH * kF * kD * kPpad) return;
  const int n = idx % kPpad;
  const int j = (idx / kPpad) & 63;
  const int f = (idx / (kPpad * kD)) & 7;
  const int bh = idx / (kPpad * kD * kF);
  const int b = bh / kH, h = bh % kH;
  float v = 0.f;
  if (n < kP)
    v = qkv[(size_t)(b * kN + 1 + f * kP + n) * k3C + 2 * kC + h * kD + j];
  Vt[idx] = f2bf(v);
}

// ---------- spatial attention via MFMA -> x4b (bf16) ----------
__global__ __launch_bounds__(256) void sp_attn_mfma(
    const ushort* __restrict__ Qb, const ushort* __restrict__ Kb,
    const ushort* __restrict__ Vt, ushort* __restrict__ x4b) {
  __shared__ __align__(16) ushort Pl[4][16 * kPstr];
  const int w = threadIdx.x >> 6;
  const int lane = threadIdx.x & 63;
  const int mtile = blockIdx.x * 4 + w;
  if (mtile >= 98) return;
  const int f = blockIdx.y;
  const int bh = blockIdx.z;
  const int lr = lane & 15;
  const int lg = lane >> 4;

  const ushort* qrow = Qb + ((size_t)bh * kS + mtile * 16 + lr) * kD + lg * 8;
  const bf16x8 a0 = *(const bf16x8*)qrow;
  const bf16x8 a1 = *(const bf16x8*)(qrow + 32);

  f32x4 s[13];
  const ushort* kbase = Kb + ((size_t)bh * kS + f * kP + lr) * kD + lg * 8;
#pragma unroll
  for (int nt = 0; nt < 13; ++nt) {
    const ushort* kr = kbase + (size_t)nt * 16 * kD;
    bf16x8 b0 = *(const bf16x8*)kr;
    bf16x8 b1 = *(const bf16x8*)(kr + 32);
    f32x4 acc = {0.f, 0.f, 0.f, 0.f};
    acc = __builtin_amdgcn_mfma_f32_16x16x32_bf16(a0, b0, acc, 0, 0, 0);
    acc = __builtin_amdgcn_mfma_f32_16x16x32_bf16(a1, b1, acc, 0, 0, 0);
    s[nt] = acc;
  }
  if (lr >= 4) {
    s[12][0] = -1e30f; s[12][1] = -1e30f; s[12][2] = -1e30f; s[12][3] = -1e30f;
  }

#pragma unroll
  for (int r = 0; r < 4; ++r) {
    float m = s[0][r];
#pragma unroll
    for (int nt = 1; nt < 13; ++nt) m = fmaxf(m, s[nt][r]);
#pragma unroll
    for (int o = 8; o; o >>= 1) m = fmaxf(m, __shfl_xor(m, o, 16));
    float sum = 0.f;
#pragma unroll
    for (int nt = 0; nt < 13; ++nt) {
      float p = __expf(s[nt][r] - m);
      s[nt][r] = p;
      sum += p;
    }
#pragma unroll
    for (int o = 8; o; o >>= 1) sum += __shfl_xor(sum, o, 16);
    const float inv = 1.f / sum;
    ushort* row = &Pl[w][(lg * 4 + r) * kPstr];
#pragma unroll
    for (int nt = 0; nt < 13; ++nt) row[nt * 16 + lr] = f2bf(s[nt][r] * inv);
    row[208 + lr] = 0;
  }

  bf16x8 pa[7];
  const ushort* prow = &Pl[w][lr * kPstr + lg * 8];
#pragma unroll
  for (int kt = 0; kt < 7; ++kt) pa[kt] = *(const bf16x8*)(prow + kt * 32);

  const ushort* vbase = Vt + ((size_t)(bh * kF + f) * kD + lr) * kPpad + lg * 8;
  f32x4 o[4];
#pragma unroll
  for (int nt2 = 0; nt2 < 4; ++nt2) {
    f32x4 acc = {0.f, 0.f, 0.f, 0.f};
    const ushort* vb = vbase + (size_t)nt2 * 16 * kPpad;
#pragma unroll
    for (int kt = 0; kt < 7; ++kt) {
      bf16x8 bv = *(const bf16x8*)(vb + kt * 32);
      acc = __builtin_amdgcn_mfma_f32_16x16x32_bf16(pa[kt], bv, acc, 0, 0, 0);
    }
    o[nt2] = acc;
  }

  const int b = bh / kH, h = bh % kH;
#pragma unroll
  for (int nt2 = 0; nt2 < 4; ++nt2) {
#pragma unroll
    for (int r = 0; r < 4; ++r) {
      const int srow = mtile * 16 + lg * 4 + r;
      x4b[(((size_t)(b * kS) + srow) * kF + f) * kC + h * kD + nt2 * 16 + lr] =
          f2bf(o[nt2][r]);
    }
  }
}

// ---------- CLS-token attention -> xin_b row 0 (bf16) ----------
__global__ __launch_bounds__(256) void cls_attn_k(const float* __restrict__ qkv,
                                                  ushort* __restrict__ xin_b) {
  __shared__ float logit[kN];
  __shared__ float qs[kD];
  __shared__ float red[8];
  __shared__ float pb[256];
  const int bh = blockIdx.x;
  const int b = bh / kH, h = bh % kH;
  const int tid = threadIdx.x;
  const size_t base = (size_t)b * kN * k3C;
  if (tid < kD) qs[tid] = qkv[base + h * kD + tid] * kScale;
  __syncthreads();
  float lmax = -1e30f;
  for (int n = tid; n < kN; n += 256) {
    const float* kr = qkv + base + (size_t)n * k3C + kC + h * kD;
    float acc = 0.f;
#pragma unroll
    for (int j = 0; j < kD; ++j) acc = fmaf(qs[j], kr[j], acc);
    logit[n] = acc;
    lmax = fmaxf(lmax, acc);
  }
#pragma unroll
  for (int o = 32; o; o >>= 1) lmax = fmaxf(lmax, __shfl_xor(lmax, o));
  if ((tid & 63) == 0) red[tid >> 6] = lmax;
  __syncthreads();
  lmax = fmaxf(fmaxf(red[0], red[1]), fmaxf(red[2], red[3]));
  float lsum = 0.f;
  for (int n = tid; n < kN; n += 256) {
    float p = __expf(logit[n] - lmax);
    logit[n] = p;
    lsum += p;
  }
#pragma unroll
  for (int o = 32; o; o >>= 1) lsum += __shfl_xor(lsum, o);
  if ((tid & 63) == 0) red[4 + (tid >> 6)] = lsum;
  __syncthreads();
  const float inv = 1.f / (red[4] + red[5] + red[6] + red[7]);
  const int j = tid & 63, part = tid >> 6;
  float acc = 0.f;
  for (int n = part; n < kN; n += 4)
    acc = fmaf(logit[n], qkv[base + (size_t)n * k3C + 2 * kC + h * kD + j], acc);
  pb[tid] = acc;
  __syncthreads();
  if (part == 0) {
    float o = (pb[j] + pb[64 + j] + pb[128 + j] + pb[192 + j]) * inv;
    xin_b[(size_t)(b * kN) * kC + h * kD + j] = f2bf(o);
  }
}

// ---------- xd gather (bf16 -> bf16) ----------
__global__ void xd_gather_k(const ushort* __restrict__ x4b,
                            ushort* __restrict__ xd_b) {
  const int idx = blockIdx.x * 256 + threadIdx.x;
  const int total = kB * kS * (kC / 8);
  if (idx >= total) return;
  const int row = idx / (kC / 8);
  const int cg = idx - row * (kC / 8);
  const int b = row / kS, s = row - b * kS;
  const int fq = s / kP;
  ((ulonglong2*)xd_b)[(size_t)row * (kC / 8) + cg] =
      ((const ulonglong2*)x4b)[((size_t)(b * kS + s) * kF + fq) * (kC / 8) + cg];
}

// ---------- temporal attn over F=8 ----------
__global__ __launch_bounds__(256) void attn2_k(
    const float* __restrict__ q2, const float* __restrict__ k2,
    const ushort* __restrict__ x4b, ushort* __restrict__ xin_b,
    float* __restrict__ attn2out) {
  const int item = blockIdx.x * 4 + (threadIdx.x >> 6);
  const int lane = threadIdx.x & 63;
  const int s = item % kS;
  const int t = item / kS;
  const int h = t % kH, b = t / kH;
  const float qv = q2[(size_t)(b * kS + s) * kC + h * kD + lane] * kScale;
  float l[kF];
#pragma unroll
  for (int f = 0; f < kF; ++f) {
    float p = qv * k2[((size_t)(b * kS + s) * kF + f) * kC + h * kD + lane];
#pragma unroll
    for (int o = 32; o; o >>= 1) p += __shfl_xor(p, o);
    l[f] = p;
  }
  float m = l[0];
#pragma unroll
  for (int f = 1; f < kF; ++f) m = fmaxf(m, l[f]);
  float sum = 0.f;
#pragma unroll
  for (int f = 0; f < kF; ++f) {
    l[f] = __expf(l[f] - m);
    sum += l[f];
  }
  const float inv = 1.f / sum;
  float o = 0.f;
#pragma unroll
  for (int f = 0; f < kF; ++f)
    o = fmaf(l[f] * inv,
             bf2f(x4b[((size_t)(b * kS + s) * kF + f) * kC + h * kD + lane]), o);
  if (lane < kF)
    attn2out[((size_t)(b * kH + h) * kS + s) * kF + lane] = l[lane] * inv;
  xin_b[(size_t)(b * kN + 1 + s) * kC + h * kD + lane] = f2bf(o);
}

extern "C" void kernel_launch(void* const* d_in, const int* in_sizes, int n_in,
                              void* d_out, int out_size, void* d_ws,
                              size_t ws_size, hipStream_t stream) {
  const float* x = (const float*)d_in[0];
  const float* Wqkv = (const float*)d_in[1];
  const float* Wq = (const float*)d_in[2];
  const float* Wkv = (const float*)d_in[3];
  const float* Wproj = (const float*)d_in[4];
  const float* bproj = (const float*)d_in[5];

  char* p = (char*)d_ws;
  float* qkv = (float*)p;            p += (size_t)3138 * 2304 * 4;
  float* k2 = (float*)p;             p += (size_t)25088 * 768 * 4;
  float* q2 = (float*)p;             p += (size_t)3136 * 768 * 4;
  ushort* x4b = (ushort*)p;          p += (size_t)25088 * 768 * 2;
  ushort* xin_b = (ushort*)p;        p += (size_t)3138 * 768 * 2;
  ushort* xd_b = (ushort*)p;         p += (size_t)3136 * 768 * 2;
  ushort* xb = (ushort*)p;           p += (size_t)3138 * 768 * 2;
  ushort* Wqkv_t = (ushort*)p;       p += (size_t)2304 * 768 * 2;
  ushort* Wq_t = (ushort*)p;         p += (size_t)768 * 768 * 2;
  ushort* Wk_t = (ushort*)p;         p += (size_t)768 * 768 * 2;
  ushort* Wproj_t = (ushort*)p;      p += (size_t)768 * 768 * 2;
  ushort* Qb = (ushort*)p;           p += (size_t)kBH * kS * kD * 2;
  ushort* Kb = (ushort*)p;           p += ((size_t)kBH * kS + 16) * kD * 2;
  ushort* Vt = (ushort*)p;

  float* out = (float*)d_out;
  float* attn2 = out + (size_t)kB * kN * kC;

  // 0. packs: x and all weights -> bf16 (Wt transposed)
  pack_x_k<<<(3138 * 768 / 4 + 255) / 256, 256, 0, stream>>>(x, xb, 3138 * 768 / 4);
  pack_wt_k<<<dim3(72, 24), 256, 0, stream>>>(Wqkv, Wqkv_t, 2304);
  pack_wt_k<<<dim3(24, 24), 256, 0, stream>>>(Wq, Wq_t, 768);
  pack_wt_k<<<dim3(24, 24), 256, 0, stream>>>(Wkv, Wk_t, 1536);
  pack_wt_k<<<dim3(24, 24), 256, 0, stream>>>(Wproj, Wproj_t, 768);
  // 1. qkv = x @ Wqkv   (fp32 out)
  gemm_bf16<<<dim3(18, 25), 256, 0, stream>>>(xb, Wqkv_t, nullptr, qkv, 3138,
                                              2304, 768);
  // 2. pack attention operands
  pack_qk_k<<<(kBH * kS * kD + 255) / 256, 256, 0, stream>>>(qkv, Qb, Kb);
  pack_vt_k<<<(kBH * kF * kD * kPpad + 255) / 256, 256, 0, stream>>>(qkv, Vt);
  // 3. cls attention -> xin_b row 0
  cls_attn_k<<<24, 256, 0, stream>>>(qkv, xin_b);
  // 4. spatial attention -> x4b
  sp_attn_mfma<<<dim3(25, 8, 24), 256, 0, stream>>>(Qb, Kb, Vt, x4b);
  // 5. xd gather
  xd_gather_k<<<(kB * kS * (kC / 8) + 255) / 256, 256, 0, stream>>>(x4b, xd_b);
  // 6. q2 = xd @ Wq
  gemm_bf16<<<dim3(6, 25), 256, 0, stream>>>(xd_b, Wq_t, nullptr, q2, 3136, 768,
                                             768);
  // 7. k2 = x4 @ Wkv[:, :768]
  gemm_bf16<<<dim3(6, 196), 256, 0, stream>>>(x4b, Wk_t, nullptr, k2, 25088,
                                              768, 768);
  // 8. temporal attention -> xin_b rows 1.., attn2
  attn2_k<<<9408, 256, 0, stream>>>(q2, k2, x4b, xin_b, attn2);
  // 9. out = xin @ Wproj + bproj
  gemm_bf16<<<dim3(6, 25), 256, 0, stream>>>(xin_b, Wproj_t, bproj, out, 3138,
                                             768, 768);
}

// Round 4
// 333.747 us; speedup vs baseline: 4.7588x; 1.2437x over previous
//
#include <hip/hip_runtime.h>

namespace {
constexpr int kB = 2;
constexpr int kH = 12;
constexpr int kD = 64;
constexpr int kC = 768;
constexpr int kF = 8;
constexpr int kP = 196;
constexpr int kS = kF * kP;      // 1568
constexpr int kN = 1 + kS;       // 1569
constexpr int k3C = 3 * kC;      // 2304
constexpr float kScale = 0.125f; // d^-0.5
constexpr int kBH = kB * kH;     // 24
constexpr int kPpad = 224;       // keys padded for PV K-dim (7x32)
constexpr int kPstr = 232;       // P LDS row stride (bf16)
constexpr int kLpad = 1600;      // cls logits row stride
}

typedef __attribute__((ext_vector_type(8))) short bf16x8;
typedef __attribute__((ext_vector_type(4))) float f32x4;

__device__ inline ushort f2bf(float x) {
  union { float f; unsigned u; } v{x};
  unsigned r = v.u + 0x7fff + ((v.u >> 16) & 1);
  return (ushort)(r >> 16);
}
__device__ inline float bf2f(ushort u) {
  union { unsigned u; float f; } v{(unsigned)u << 16};
  return v.f;
}

__device__ __forceinline__ void gload_lds16(const void* g, void* l) {
  __builtin_amdgcn_global_load_lds(
      (const __attribute__((address_space(1))) unsigned int*)g,
      (__attribute__((address_space(3))) unsigned int*)l, 16, 0, 0);
}

// ---------- bf16 MFMA GEMM: C[M,N]f32 = A[M,K]bf16 @ Bt[N,K]bf16^T (+bias) ----
__global__ __launch_bounds__(256) void gemm_bf16(
    const ushort* __restrict__ A, const ushort* __restrict__ Bt,
    const float* __restrict__ bias, float* __restrict__ C,
    int M, int N, int K) {
  __shared__ __align__(16) ushort As[128 * 32];
  __shared__ __align__(16) ushort Bs[128 * 32];
  const int tid = threadIdx.x;
  const int m0 = blockIdx.y * 128, n0 = blockIdx.x * 128;
  const int r0 = tid >> 2, c0 = tid & 3;
  const int r1 = r0 + 64;
  const int sc0 = (c0 ^ ((r0 >> 1) & 3)) * 8;
  const int sc1 = (c0 ^ ((r1 >> 1) & 3)) * 8;
  const int ar0 = min(m0 + r0, M - 1), ar1 = min(m0 + r1, M - 1);
  const ushort* ga0 = A + (size_t)ar0 * K + sc0;
  const ushort* ga1 = A + (size_t)ar1 * K + sc1;
  const ushort* gb0 = Bt + (size_t)(n0 + r0) * K + sc0;
  const ushort* gb1 = Bt + (size_t)(n0 + r1) * K + sc1;
  const int w = tid >> 6;
  char* lA0 = (char*)As + w * 1024;
  char* lA1 = (char*)As + 4096 + w * 1024;
  char* lB0 = (char*)Bs + w * 1024;
  char* lB1 = (char*)Bs + 4096 + w * 1024;
  const int lane = tid & 63;
  const int lr = lane & 15, lg = lane >> 4;
  const int wr = w >> 1, wc = w & 1;
  f32x4 acc[4][4] = {};
  for (int kt = 0; kt < K; kt += 32) {
    gload_lds16(ga0 + kt, lA0);
    gload_lds16(ga1 + kt, lA1);
    gload_lds16(gb0 + kt, lB0);
    gload_lds16(gb1 + kt, lB1);
    __syncthreads();
    bf16x8 af[4], bfr[4];
#pragma unroll
    for (int m = 0; m < 4; ++m) {
      int row = wr * 64 + m * 16 + lr;
      int ch = lg ^ ((row >> 1) & 3);
      af[m] = *(const bf16x8*)(As + row * 32 + ch * 8);
    }
#pragma unroll
    for (int n = 0; n < 4; ++n) {
      int row = wc * 64 + n * 16 + lr;
      int ch = lg ^ ((row >> 1) & 3);
      bfr[n] = *(const bf16x8*)(Bs + row * 32 + ch * 8);
    }
#pragma unroll
    for (int m = 0; m < 4; ++m)
#pragma unroll
      for (int n = 0; n < 4; ++n)
        acc[m][n] =
            __builtin_amdgcn_mfma_f32_16x16x32_bf16(af[m], bfr[n], acc[m][n], 0, 0, 0);
    __syncthreads();
  }
#pragma unroll
  for (int m = 0; m < 4; ++m) {
#pragma unroll
    for (int r = 0; r < 4; ++r) {
      const int mg = m0 + wr * 64 + m * 16 + lg * 4 + r;
      if (mg < M) {
        float* crow = C + (size_t)mg * N + n0 + wc * 64 + lr;
#pragma unroll
        for (int n = 0; n < 4; ++n) {
          float v = acc[m][n][r];
          if (bias) v += bias[n0 + wc * 64 + n * 16 + lr];
          crow[n * 16] = v;
        }
      }
    }
  }
}

// ---------- pack x -> bf16 ----------
__global__ void pack_x_k(const float* __restrict__ X, ushort* __restrict__ Xb,
                         int n4) {
  const int i = blockIdx.x * 256 + threadIdx.x;
  if (i >= n4) return;
  float4 v = ((const float4*)X)[i];
  ushort4 o = {f2bf(v.x), f2bf(v.y), f2bf(v.z), f2bf(v.w)};
  ((ushort4*)Xb)[i] = o;
}

// ---------- pack W[768][ldw] cols[0,Ncols) -> Wt[Ncols][768] bf16 ----------
__global__ __launch_bounds__(256) void pack_wt_k(const float* __restrict__ W,
                                                 ushort* __restrict__ Wt,
                                                 int ldw) {
  __shared__ float t[32][33];
  const int nb = blockIdx.x * 32;
  const int kb = blockIdx.y * 32;
  const int tx = threadIdx.x & 31, ty = threadIdx.x >> 5;
#pragma unroll
  for (int i = 0; i < 32; i += 8)
    t[ty + i][tx] = W[(size_t)(kb + ty + i) * ldw + nb + tx];
  __syncthreads();
#pragma unroll
  for (int i = 0; i < 32; i += 8)
    Wt[(size_t)(nb + ty + i) * 768 + kb + tx] = f2bf(t[tx][ty + i]);
}

// ---------- pack q,k (scaled q) into bf16 row-major [bh][1568][64] ----------
__global__ void pack_qk_k(const float* __restrict__ qkv, ushort* __restrict__ Qb,
                          ushort* __restrict__ Kb) {
  const int idx = blockIdx.x * 256 + threadIdx.x;
  if (idx >= kBH * kS * kD) return;
  const int j = idx & 63;
  const int s = (idx >> 6) % kS;
  const int bh = idx / (kS * kD);
  const int b = bh / kH, h = bh % kH;
  const size_t src = (size_t)(b * kN + 1 + s) * k3C + h * kD + j;
  Qb[idx] = f2bf(qkv[src] * kScale);
  Kb[idx] = f2bf(qkv[src + kC]);
}

// ---------- pack V transposed: Vt[bh*8+f][64][224] bf16 ----------
__global__ void pack_vt_k(const float* __restrict__ qkv, ushort* __restrict__ Vt) {
  const int idx = blockIdx.x * 256 + threadIdx.x;
  if (idx >= kBH * kF * kD * kPpad) return;
  const int n = idx % kPpad;
  const int j = (idx / kPpad) & 63;
  const int f = (idx / (kPpad * kD)) & 7;
  const int bh = idx / (kPpad * kD * kF);
  const int b = bh / kH, h = bh % kH;
  float v = 0.f;
  if (n < kP)
    v = qkv[(size_t)(b * kN + 1 + f * kP + n) * k3C + 2 * kC + h * kD + j];
  Vt[idx] = f2bf(v);
}

// ---------- spatial attention via MFMA -> x4b (bf16) ----------
__global__ __launch_bounds__(256) void sp_attn_mfma(
    const ushort* __restrict__ Qb, const ushort* __restrict__ Kb,
    const ushort* __restrict__ Vt, ushort* __restrict__ x4b) {
  __shared__ __align__(16) ushort Pl[4][16 * kPstr];
  const int w = threadIdx.x >> 6;
  const int lane = threadIdx.x & 63;
  const int mtile = blockIdx.x * 4 + w;
  if (mtile >= 98) return;
  const int f = blockIdx.y;
  const int bh = blockIdx.z;
  const int lr = lane & 15;
  const int lg = lane >> 4;

  const ushort* qrow = Qb + ((size_t)bh * kS + mtile * 16 + lr) * kD + lg * 8;
  const bf16x8 a0 = *(const bf16x8*)qrow;
  const bf16x8 a1 = *(const bf16x8*)(qrow + 32);

  f32x4 s[13];
  const ushort* kbase = Kb + ((size_t)bh * kS + f * kP + lr) * kD + lg * 8;
#pragma unroll
  for (int nt = 0; nt < 13; ++nt) {
    const ushort* kr = kbase + (size_t)nt * 16 * kD;
    bf16x8 b0 = *(const bf16x8*)kr;
    bf16x8 b1 = *(const bf16x8*)(kr + 32);
    f32x4 acc = {0.f, 0.f, 0.f, 0.f};
    acc = __builtin_amdgcn_mfma_f32_16x16x32_bf16(a0, b0, acc, 0, 0, 0);
    acc = __builtin_amdgcn_mfma_f32_16x16x32_bf16(a1, b1, acc, 0, 0, 0);
    s[nt] = acc;
  }
  if (lr >= 4) {
    s[12][0] = -1e30f; s[12][1] = -1e30f; s[12][2] = -1e30f; s[12][3] = -1e30f;
  }

#pragma unroll
  for (int r = 0; r < 4; ++r) {
    float m = s[0][r];
#pragma unroll
    for (int nt = 1; nt < 13; ++nt) m = fmaxf(m, s[nt][r]);
#pragma unroll
    for (int o = 8; o; o >>= 1) m = fmaxf(m, __shfl_xor(m, o, 16));
    float sum = 0.f;
#pragma unroll
    for (int nt = 0; nt < 13; ++nt) {
      float p = __expf(s[nt][r] - m);
      s[nt][r] = p;
      sum += p;
    }
#pragma unroll
    for (int o = 8; o; o >>= 1) sum += __shfl_xor(sum, o, 16);
    const float inv = 1.f / sum;
    ushort* row = &Pl[w][(lg * 4 + r) * kPstr];
#pragma unroll
    for (int nt = 0; nt < 13; ++nt) row[nt * 16 + lr] = f2bf(s[nt][r] * inv);
    row[208 + lr] = 0;
  }

  bf16x8 pa[7];
  const ushort* prow = &Pl[w][lr * kPstr + lg * 8];
#pragma unroll
  for (int kt = 0; kt < 7; ++kt) pa[kt] = *(const bf16x8*)(prow + kt * 32);

  const ushort* vbase = Vt + ((size_t)(bh * kF + f) * kD + lr) * kPpad + lg * 8;
  f32x4 o[4];
#pragma unroll
  for (int nt2 = 0; nt2 < 4; ++nt2) {
    f32x4 acc = {0.f, 0.f, 0.f, 0.f};
    const ushort* vb = vbase + (size_t)nt2 * 16 * kPpad;
#pragma unroll
    for (int kt = 0; kt < 7; ++kt) {
      bf16x8 bv = *(const bf16x8*)(vb + kt * 32);
      acc = __builtin_amdgcn_mfma_f32_16x16x32_bf16(pa[kt], bv, acc, 0, 0, 0);
    }
    o[nt2] = acc;
  }

  const int b = bh / kH, h = bh % kH;
#pragma unroll
  for (int nt2 = 0; nt2 < 4; ++nt2) {
#pragma unroll
    for (int r = 0; r < 4; ++r) {
      const int srow = mtile * 16 + lg * 4 + r;
      x4b[(((size_t)(b * kS) + srow) * kF + f) * kC + h * kD + nt2 * 16 + lr] =
          f2bf(o[nt2][r]);
    }
  }
}

// ---------- cls attention, 4-phase parallel ----------
// A: logits[bh][n] = (q_cls*scale) . K[n]  -- 16-lane group per key
__global__ __launch_bounds__(256) void cls_logits_k(const float* __restrict__ qkv,
                                                    float* __restrict__ logits) {
  const int chunk = blockIdx.x, bh = blockIdx.y;
  const int b = bh / kH, h = bh % kH;
  const int g = threadIdx.x & 15, row = threadIdx.x >> 4;
  const size_t base = (size_t)b * kN * k3C;
  float4 q4 = *(const float4*)(qkv + base + h * kD + g * 4);
  q4.x *= kScale; q4.y *= kScale; q4.z *= kScale; q4.w *= kScale;
#pragma unroll
  for (int i = 0; i < 16; ++i) {
    const int n = chunk * 256 + i * 16 + row;
    if (n < kN) {
      const float4 kv =
          *(const float4*)(qkv + base + (size_t)n * k3C + kC + h * kD + g * 4);
      float p = q4.x * kv.x + q4.y * kv.y + q4.z * kv.z + q4.w * kv.w;
#pragma unroll
      for (int o = 8; o; o >>= 1) p += __shfl_xor(p, o, 16);
      if (g == 0) logits[bh * kLpad + n] = p;
    }
  }
}

// B: softmax over 1569 logits -> normalized p
__global__ __launch_bounds__(256) void cls_softmax_k(const float* __restrict__ logits,
                                                     float* __restrict__ pbuf) {
  __shared__ float red[8];
  const int bh = blockIdx.x, tid = threadIdx.x;
  float m = -1e30f;
  for (int n = tid; n < kN; n += 256) m = fmaxf(m, logits[bh * kLpad + n]);
#pragma unroll
  for (int o = 32; o; o >>= 1) m = fmaxf(m, __shfl_xor(m, o));
  if ((tid & 63) == 0) red[tid >> 6] = m;
  __syncthreads();
  m = fmaxf(fmaxf(red[0], red[1]), fmaxf(red[2], red[3]));
  float sum = 0.f;
  for (int n = tid; n < kN; n += 256) sum += __expf(logits[bh * kLpad + n] - m);
#pragma unroll
  for (int o = 32; o; o >>= 1) sum += __shfl_xor(sum, o);
  if ((tid & 63) == 0) red[4 + (tid >> 6)] = sum;
  __syncthreads();
  const float inv = 1.f / (red[4] + red[5] + red[6] + red[7]);
  for (int n = tid; n < kN; n += 256)
    pbuf[bh * kLpad + n] = __expf(logits[bh * kLpad + n] - m) * inv;
}

// C: partial[bh][chunk][j] = sum_{n in chunk} p[n] * V[n][j]
__global__ __launch_bounds__(256) void cls_pv_k(const float* __restrict__ qkv,
                                                const float* __restrict__ pbuf,
                                                float* __restrict__ partial) {
  __shared__ float pb[256];
  const int chunk = blockIdx.x, bh = blockIdx.y;
  const int b = bh / kH, h = bh % kH;
  const int j = threadIdx.x & 63, part = threadIdx.x >> 6;
  const size_t base = (size_t)b * kN * k3C + 2 * kC + h * kD + j;
  float acc = 0.f;
#pragma unroll 4
  for (int i = 0; i < 64; ++i) {
    const int n = chunk * 256 + i * 4 + part;
    if (n < kN) acc = fmaf(pbuf[bh * kLpad + n], qkv[base + (size_t)n * k3C], acc);
  }
  pb[threadIdx.x] = acc;
  __syncthreads();
  if (part == 0)
    partial[((size_t)bh * 7 + chunk) * kD + j] =
        pb[j] + pb[64 + j] + pb[128 + j] + pb[192 + j];
}

// D: reduce 7 chunks -> xin_b row 0
__global__ void cls_red_k(const float* __restrict__ partial,
                          ushort* __restrict__ xin_b) {
  const int bh = blockIdx.x, j = threadIdx.x;
  const int b = bh / kH, h = bh % kH;
  float s = 0.f;
#pragma unroll
  for (int c = 0; c < 7; ++c) s += partial[((size_t)bh * 7 + c) * kD + j];
  xin_b[(size_t)(b * kN) * kC + h * kD + j] = f2bf(s);
}

// ---------- xd gather (bf16 -> bf16) ----------
__global__ void xd_gather_k(const ushort* __restrict__ x4b,
                            ushort* __restrict__ xd_b) {
  const int idx = blockIdx.x * 256 + threadIdx.x;
  const int total = kB * kS * (kC / 8);
  if (idx >= total) return;
  const int row = idx / (kC / 8);
  const int cg = idx - row * (kC / 8);
  const int b = row / kS, s = row - b * kS;
  const int fq = s / kP;
  ((ulonglong2*)xd_b)[(size_t)row * (kC / 8) + cg] =
      ((const ulonglong2*)x4b)[((size_t)(b * kS + s) * kF + fq) * (kC / 8) + cg];
}

// ---------- temporal attn over F=8 ----------
__global__ __launch_bounds__(256) void attn2_k(
    const float* __restrict__ q2, const float* __restrict__ k2,
    const ushort* __restrict__ x4b, ushort* __restrict__ xin_b,
    float* __restrict__ attn2out) {
  const int item = blockIdx.x * 4 + (threadIdx.x >> 6);
  const int lane = threadIdx.x & 63;
  const int s = item % kS;
  const int t = item / kS;
  const int h = t % kH, b = t / kH;
  const float qv = q2[(size_t)(b * kS + s) * kC + h * kD + lane] * kScale;
  float l[kF];
#pragma unroll
  for (int f = 0; f < kF; ++f) {
    float p = qv * k2[((size_t)(b * kS + s) * kF + f) * kC + h * kD + lane];
#pragma unroll
    for (int o = 32; o; o >>= 1) p += __shfl_xor(p, o);
    l[f] = p;
  }
  float m = l[0];
#pragma unroll
  for (int f = 1; f < kF; ++f) m = fmaxf(m, l[f]);
  float sum = 0.f;
#pragma unroll
  for (int f = 0; f < kF; ++f) {
    l[f] = __expf(l[f] - m);
    sum += l[f];
  }
  const float inv = 1.f / sum;
  float o = 0.f;
#pragma unroll
  for (int f = 0; f < kF; ++f)
    o = fmaf(l[f] * inv,
             bf2f(x4b[((size_t)(b * kS + s) * kF + f) * kC + h * kD + lane]), o);
  if (lane < kF)
    attn2out[((size_t)(b * kH + h) * kS + s) * kF + lane] = l[lane] * inv;
  xin_b[(size_t)(b * kN + 1 + s) * kC + h * kD + lane] = f2bf(o);
}

extern "C" void kernel_launch(void* const* d_in, const int* in_sizes, int n_in,
                              void* d_out, int out_size, void* d_ws,
                              size_t ws_size, hipStream_t stream) {
  const float* x = (const float*)d_in[0];
  const float* Wqkv = (const float*)d_in[1];
  const float* Wq = (const float*)d_in[2];
  const float* Wkv = (const float*)d_in[3];
  const float* Wproj = (const float*)d_in[4];
  const float* bproj = (const float*)d_in[5];

  char* p = (char*)d_ws;
  float* qkv = (float*)p;            p += (size_t)3138 * 2304 * 4;
  float* k2 = (float*)p;             p += (size_t)25088 * 768 * 4;
  float* q2 = (float*)p;             p += (size_t)3136 * 768 * 4;
  ushort* x4b = (ushort*)p;          p += (size_t)25088 * 768 * 2;
  ushort* xin_b = (ushort*)p;        p += (size_t)3138 * 768 * 2;
  ushort* xd_b = (ushort*)p;         p += (size_t)3136 * 768 * 2;
  ushort* xb = (ushort*)p;           p += (size_t)3138 * 768 * 2;
  ushort* Wqkv_t = (ushort*)p;       p += (size_t)2304 * 768 * 2;
  ushort* Wq_t = (ushort*)p;         p += (size_t)768 * 768 * 2;
  ushort* Wk_t = (ushort*)p;         p += (size_t)768 * 768 * 2;
  ushort* Wproj_t = (ushort*)p;      p += (size_t)768 * 768 * 2;
  ushort* Qb = (ushort*)p;           p += (size_t)kBH * kS * kD * 2;
  ushort* Kb = (ushort*)p;           p += ((size_t)kBH * kS + 16) * kD * 2;
  ushort* Vt = (ushort*)p;           p += (size_t)kBH * kF * kD * kPpad * 2;
  float* clsL = (float*)p;           p += (size_t)kBH * kLpad * 4;
  float* clsP = (float*)p;           p += (size_t)kBH * kLpad * 4;
  float* clsPart = (float*)p;

  float* out = (float*)d_out;
  float* attn2 = out + (size_t)kB * kN * kC;

  // 0. packs: x and all weights -> bf16 (Wt transposed)
  pack_x_k<<<(3138 * 768 / 4 + 255) / 256, 256, 0, stream>>>(x, xb, 3138 * 768 / 4);
  pack_wt_k<<<dim3(72, 24), 256, 0, stream>>>(Wqkv, Wqkv_t, 2304);
  pack_wt_k<<<dim3(24, 24), 256, 0, stream>>>(Wq, Wq_t, 768);
  pack_wt_k<<<dim3(24, 24), 256, 0, stream>>>(Wkv, Wk_t, 1536);
  pack_wt_k<<<dim3(24, 24), 256, 0, stream>>>(Wproj, Wproj_t, 768);
  // 1. qkv = x @ Wqkv   (fp32 out)
  gemm_bf16<<<dim3(18, 25), 256, 0, stream>>>(xb, Wqkv_t, nullptr, qkv, 3138,
                                              2304, 768);
  // 2. pack attention operands
  pack_qk_k<<<(kBH * kS * kD + 255) / 256, 256, 0, stream>>>(qkv, Qb, Kb);
  pack_vt_k<<<(kBH * kF * kD * kPpad + 255) / 256, 256, 0, stream>>>(qkv, Vt);
  // 3. cls attention (4-phase) -> xin_b row 0
  cls_logits_k<<<dim3(7, 24), 256, 0, stream>>>(qkv, clsL);
  cls_softmax_k<<<24, 256, 0, stream>>>(clsL, clsP);
  cls_pv_k<<<dim3(7, 24), 256, 0, stream>>>(qkv, clsP, clsPart);
  cls_red_k<<<24, 64, 0, stream>>>(clsPart, xin_b);
  // 4. spatial attention -> x4b
  sp_attn_mfma<<<dim3(25, 8, 24), 256, 0, stream>>>(Qb, Kb, Vt, x4b);
  // 5. xd gather
  xd_gather_k<<<(kB * kS * (kC / 8) + 255) / 256, 256, 0, stream>>>(x4b, xd_b);
  // 6. q2 = xd @ Wq
  gemm_bf16<<<dim3(6, 25), 256, 0, stream>>>(xd_b, Wq_t, nullptr, q2, 3136, 768,
                                             768);
  // 7. k2 = x4 @ Wkv[:, :768]
  gemm_bf16<<<dim3(6, 196), 256, 0, stream>>>(x4b, Wk_t, nullptr, k2, 25088,
                                              768, 768);
  // 8. temporal attention -> xin_b rows 1.., attn2
  attn2_k<<<9408, 256, 0, stream>>>(q2, k2, x4b, xin_b, attn2);
  // 9. out = xin @ Wproj + bproj
  gemm_bf16<<<dim3(6, 25), 256, 0, stream>>>(xin_b, Wproj_t, bproj, out, 3138,
                                             768, 768);
}

// Round 5
// 296.301 us; speedup vs baseline: 5.3602x; 1.1264x over previous
//
#include <hip/hip_runtime.h>

namespace {
constexpr int kB = 2;
constexpr int kH = 12;
constexpr int kD = 64;
constexpr int kC = 768;
constexpr int kF = 8;
constexpr int kP = 196;
constexpr int kS = kF * kP;      // 1568
constexpr int kN = 1 + kS;       // 1569
constexpr int k3C = 3 * kC;      // 2304
constexpr float kScale = 0.125f; // d^-0.5
constexpr int kBH = kB * kH;     // 24
constexpr int kPpad = 224;       // keys padded for PV K-dim (7x32)
constexpr int kPstr = 232;       // P LDS row stride (bf16): 116 dwords ≡ 20 mod 32 -> 8-bank spread
constexpr int kLpad = 1600;      // cls logits row stride
}

typedef __attribute__((ext_vector_type(8))) short bf16x8;
typedef __attribute__((ext_vector_type(4))) float f32x4;

__device__ inline ushort f2bf(float x) {
  union { float f; unsigned u; } v{x};
  unsigned r = v.u + 0x7fff + ((v.u >> 16) & 1);
  return (ushort)(r >> 16);
}
__device__ inline float bf2f(ushort u) {
  union { unsigned u; float f; } v{(unsigned)u << 16};
  return v.f;
}

__device__ __forceinline__ void gload_lds16(const void* g, void* l) {
  __builtin_amdgcn_global_load_lds(
      (const __attribute__((address_space(1))) unsigned int*)g,
      (__attribute__((address_space(3))) unsigned int*)l, 16, 0, 0);
}

// ---------- bf16 MFMA GEMM: C[M,N]f32 = A[M,K]bf16 @ Bt[N,K]bf16^T (+bias) ----
// 1-D grid with m204-bijective XCD remap: contiguous M-panels per XCD.
__global__ __launch_bounds__(256) void gemm_bf16(
    const ushort* __restrict__ A, const ushort* __restrict__ Bt,
    const float* __restrict__ bias, float* __restrict__ C,
    int M, int N, int K, int nbx) {
  // bijective XCD remap (m204): XCD k = lid%8 gets a contiguous vid chunk
  const int nwg = gridDim.x;
  const int q = nwg >> 3, rr = nwg & 7;
  const int xcd = blockIdx.x & 7, loc = blockIdx.x >> 3;
  const int vid = ((xcd < rr) ? xcd * (q + 1) : rr * (q + 1) + (xcd - rr) * q) + loc;
  const int m0 = (vid / nbx) * 128, n0 = (vid % nbx) * 128;

  __shared__ __align__(16) ushort As[128 * 32];
  __shared__ __align__(16) ushort Bs[128 * 32];
  const int tid = threadIdx.x;
  const int r0 = tid >> 2, c0 = tid & 3;
  const int r1 = r0 + 64;
  const int sc0 = (c0 ^ ((r0 >> 1) & 3)) * 8;
  const int sc1 = (c0 ^ ((r1 >> 1) & 3)) * 8;
  const int ar0 = min(m0 + r0, M - 1), ar1 = min(m0 + r1, M - 1);
  const ushort* ga0 = A + (size_t)ar0 * K + sc0;
  const ushort* ga1 = A + (size_t)ar1 * K + sc1;
  const ushort* gb0 = Bt + (size_t)(n0 + r0) * K + sc0;
  const ushort* gb1 = Bt + (size_t)(n0 + r1) * K + sc1;
  const int w = tid >> 6;
  char* lA0 = (char*)As + w * 1024;
  char* lA1 = (char*)As + 4096 + w * 1024;
  char* lB0 = (char*)Bs + w * 1024;
  char* lB1 = (char*)Bs + 4096 + w * 1024;
  const int lane = tid & 63;
  const int lr = lane & 15, lg = lane >> 4;
  const int wr = w >> 1, wc = w & 1;
  f32x4 acc[4][4] = {};
  for (int kt = 0; kt < K; kt += 32) {
    gload_lds16(ga0 + kt, lA0);
    gload_lds16(ga1 + kt, lA1);
    gload_lds16(gb0 + kt, lB0);
    gload_lds16(gb1 + kt, lB1);
    __syncthreads();
    bf16x8 af[4], bfr[4];
#pragma unroll
    for (int m = 0; m < 4; ++m) {
      int row = wr * 64 + m * 16 + lr;
      int ch = lg ^ ((row >> 1) & 3);
      af[m] = *(const bf16x8*)(As + row * 32 + ch * 8);
    }
#pragma unroll
    for (int n = 0; n < 4; ++n) {
      int row = wc * 64 + n * 16 + lr;
      int ch = lg ^ ((row >> 1) & 3);
      bfr[n] = *(const bf16x8*)(Bs + row * 32 + ch * 8);
    }
#pragma unroll
    for (int m = 0; m < 4; ++m)
#pragma unroll
      for (int n = 0; n < 4; ++n)
        acc[m][n] =
            __builtin_amdgcn_mfma_f32_16x16x32_bf16(af[m], bfr[n], acc[m][n], 0, 0, 0);
    __syncthreads();
  }
#pragma unroll
  for (int m = 0; m < 4; ++m) {
#pragma unroll
    for (int r = 0; r < 4; ++r) {
      const int mg = m0 + wr * 64 + m * 16 + lg * 4 + r;
      if (mg < M) {
        float* crow = C + (size_t)mg * N + n0 + wc * 64 + lr;
#pragma unroll
        for (int n = 0; n < 4; ++n) {
          float v = acc[m][n][r];
          if (bias) v += bias[n0 + wc * 64 + n * 16 + lr];
          crow[n * 16] = v;
        }
      }
    }
  }
}

// ---------- pack x -> bf16 ----------
__global__ void pack_x_k(const float* __restrict__ X, ushort* __restrict__ Xb,
                         int n4) {
  const int i = blockIdx.x * 256 + threadIdx.x;
  if (i >= n4) return;
  float4 v = ((const float4*)X)[i];
  ushort4 o = {f2bf(v.x), f2bf(v.y), f2bf(v.z), f2bf(v.w)};
  ((ushort4*)Xb)[i] = o;
}

// ---------- pack W[768][ldw] cols[0,Ncols) -> Wt[Ncols][768] bf16 ----------
__global__ __launch_bounds__(256) void pack_wt_k(const float* __restrict__ W,
                                                 ushort* __restrict__ Wt,
                                                 int ldw) {
  __shared__ float t[32][33];
  const int nb = blockIdx.x * 32;
  const int kb = blockIdx.y * 32;
  const int tx = threadIdx.x & 31, ty = threadIdx.x >> 5;
#pragma unroll
  for (int i = 0; i < 32; i += 8)
    t[ty + i][tx] = W[(size_t)(kb + ty + i) * ldw + nb + tx];
  __syncthreads();
#pragma unroll
  for (int i = 0; i < 32; i += 8)
    Wt[(size_t)(nb + ty + i) * 768 + kb + tx] = f2bf(t[tx][ty + i]);
}

// ---------- pack q,k (scaled q) into bf16 row-major [bh][1568][64] ----------
__global__ void pack_qk_k(const float* __restrict__ qkv, ushort* __restrict__ Qb,
                          ushort* __restrict__ Kb) {
  const int idx = blockIdx.x * 256 + threadIdx.x;
  if (idx >= kBH * kS * kD) return;
  const int j = idx & 63;
  const int s = (idx >> 6) % kS;
  const int bh = idx / (kS * kD);
  const int b = bh / kH, h = bh % kH;
  const size_t src = (size_t)(b * kN + 1 + s) * k3C + h * kD + j;
  Qb[idx] = f2bf(qkv[src] * kScale);
  Kb[idx] = f2bf(qkv[src + kC]);
}

// ---------- pack V transposed: Vt[bh*8+f][64][224] bf16 ----------
__global__ void pack_vt_k(const float* __restrict__ qkv, ushort* __restrict__ Vt) {
  const int idx = blockIdx.x * 256 + threadIdx.x;
  if (idx >= kBH * kF * kD * kPpad) return;
  const int n = idx % kPpad;
  const int j = (idx / kPpad) & 63;
  const int f = (idx / (kPpad * kD)) & 7;
  const int bh = idx / (kPpad * kD * kF);
  const int b = bh / kH, h = bh % kH;
  float v = 0.f;
  if (n < kP)
    v = qkv[(size_t)(b * kN + 1 + f * kP + n) * k3C + 2 * kC + h * kD + j];
  Vt[idx] = f2bf(v);
}

// ---------- spatial attention via MFMA, 32 queries/wave -> x4b (bf16) ----------
// grid (192 = f*24+bh, 25), 2 waves/block. XCD = blockIdx.x%8 = bh%8 -> K/V/Q L2-resident.
__global__ __launch_bounds__(128) void sp_attn_mfma(
    const ushort* __restrict__ Qb, const ushort* __restrict__ Kb,
    const ushort* __restrict__ Vt, ushort* __restrict__ x4b) {
  __shared__ __align__(16) ushort Pl[2][32 * kPstr];
  const int w = threadIdx.x >> 6;
  const int lane = threadIdx.x & 63;
  const int fbh = blockIdx.x;
  const int f = fbh / 24, bh = fbh % 24;
  const int tile = blockIdx.y * 2 + w;   // 32-query tile, 0..48 valid
  if (tile >= 49) return;
  const int q0 = tile * 32;
  const int lr = lane & 15;
  const int lg = lane >> 4;

  // Q fragments for both 16-row halves
  const ushort* qrow = Qb + ((size_t)bh * kS + q0 + lr) * kD + lg * 8;
  const bf16x8 a00 = *(const bf16x8*)qrow;
  const bf16x8 a01 = *(const bf16x8*)(qrow + 32);
  const bf16x8 a10 = *(const bf16x8*)(qrow + 16 * kD);
  const bf16x8 a11 = *(const bf16x8*)(qrow + 16 * kD + 32);

  // S = Q @ K^T : 13 N-tiles cover 208 >= 196 keys; K loads shared by both halves
  f32x4 s0[13], s1[13];
  const ushort* kbase = Kb + ((size_t)bh * kS + f * kP + lr) * kD + lg * 8;
#pragma unroll
  for (int nt = 0; nt < 13; ++nt) {
    const ushort* kr = kbase + (size_t)nt * 16 * kD;
    bf16x8 b0 = *(const bf16x8*)kr;
    bf16x8 b1 = *(const bf16x8*)(kr + 32);
    f32x4 acc0 = {0.f, 0.f, 0.f, 0.f}, acc1 = {0.f, 0.f, 0.f, 0.f};
    acc0 = __builtin_amdgcn_mfma_f32_16x16x32_bf16(a00, b0, acc0, 0, 0, 0);
    acc0 = __builtin_amdgcn_mfma_f32_16x16x32_bf16(a01, b1, acc0, 0, 0, 0);
    acc1 = __builtin_amdgcn_mfma_f32_16x16x32_bf16(a10, b0, acc1, 0, 0, 0);
    acc1 = __builtin_amdgcn_mfma_f32_16x16x32_bf16(a11, b1, acc1, 0, 0, 0);
    s0[nt] = acc0;
    s1[nt] = acc1;
  }
  if (lr >= 4) {
#pragma unroll
    for (int r = 0; r < 4; ++r) { s0[12][r] = -1e30f; s1[12][r] = -1e30f; }
  }

  // softmax per output row (row = m*16 + lg*4 + r); unnormalized P, keep inv
  float inv0[4], inv1[4];
#pragma unroll
  for (int r = 0; r < 4; ++r) {
    float m = fmaxf(s0[0][r], s1[0][r]);
    float m0v = s0[0][r], m1v = s1[0][r];
#pragma unroll
    for (int nt = 1; nt < 13; ++nt) {
      m0v = fmaxf(m0v, s0[nt][r]);
      m1v = fmaxf(m1v, s1[nt][r]);
    }
#pragma unroll
    for (int o = 8; o; o >>= 1) {
      m0v = fmaxf(m0v, __shfl_xor(m0v, o, 16));
      m1v = fmaxf(m1v, __shfl_xor(m1v, o, 16));
    }
    float sum0 = 0.f, sum1 = 0.f;
    ushort* row0 = &Pl[w][(lg * 4 + r) * kPstr];
    ushort* row1 = &Pl[w][(16 + lg * 4 + r) * kPstr];
#pragma unroll
    for (int nt = 0; nt < 13; ++nt) {
      float p0 = __expf(s0[nt][r] - m0v);
      float p1 = __expf(s1[nt][r] - m1v);
      sum0 += p0;
      sum1 += p1;
      row0[nt * 16 + lr] = f2bf(p0);
      row1[nt * 16 + lr] = f2bf(p1);
    }
    row0[208 + lr] = 0;
    row1[208 + lr] = 0;
#pragma unroll
    for (int o = 8; o; o >>= 1) {
      sum0 += __shfl_xor(sum0, o, 16);
      sum1 += __shfl_xor(sum1, o, 16);
    }
    inv0[r] = 1.f / sum0;
    inv1[r] = 1.f / sum1;
  }

  // O = P @ V ; kt-outer so only one P-frag pair is live at a time
  const ushort* prow0 = &Pl[w][lr * kPstr + lg * 8];
  const ushort* prow1 = &Pl[w][(16 + lr) * kPstr + lg * 8];
  const ushort* vbase = Vt + ((size_t)(bh * kF + f) * kD + lr) * kPpad + lg * 8;
  f32x4 o0[4] = {}, o1[4] = {};
#pragma unroll
  for (int kt = 0; kt < 7; ++kt) {
    bf16x8 pa0 = *(const bf16x8*)(prow0 + kt * 32);
    bf16x8 pa1 = *(const bf16x8*)(prow1 + kt * 32);
#pragma unroll
    for (int nt2 = 0; nt2 < 4; ++nt2) {
      bf16x8 bv = *(const bf16x8*)(vbase + (size_t)nt2 * 16 * kPpad + kt * 32);
      o0[nt2] = __builtin_amdgcn_mfma_f32_16x16x32_bf16(pa0, bv, o0[nt2], 0, 0, 0);
      o1[nt2] = __builtin_amdgcn_mfma_f32_16x16x32_bf16(pa1, bv, o1[nt2], 0, 0, 0);
    }
  }

  const int b = bh / kH, h = bh % kH;
#pragma unroll
  for (int nt2 = 0; nt2 < 4; ++nt2) {
#pragma unroll
    for (int r = 0; r < 4; ++r) {
      const int srow0 = q0 + lg * 4 + r;
      x4b[(((size_t)(b * kS) + srow0) * kF + f) * kC + h * kD + nt2 * 16 + lr] =
          f2bf(o0[nt2][r] * inv0[r]);
      x4b[(((size_t)(b * kS) + srow0 + 16) * kF + f) * kC + h * kD + nt2 * 16 + lr] =
          f2bf(o1[nt2][r] * inv1[r]);
    }
  }
}

// ---------- cls attention, 4-phase parallel ----------
__global__ __launch_bounds__(256) void cls_logits_k(const float* __restrict__ qkv,
                                                    float* __restrict__ logits) {
  const int chunk = blockIdx.x, bh = blockIdx.y;
  const int b = bh / kH, h = bh % kH;
  const int g = threadIdx.x & 15, row = threadIdx.x >> 4;
  const size_t base = (size_t)b * kN * k3C;
  float4 q4 = *(const float4*)(qkv + base + h * kD + g * 4);
  q4.x *= kScale; q4.y *= kScale; q4.z *= kScale; q4.w *= kScale;
#pragma unroll
  for (int i = 0; i < 16; ++i) {
    const int n = chunk * 256 + i * 16 + row;
    if (n < kN) {
      const float4 kv =
          *(const float4*)(qkv + base + (size_t)n * k3C + kC + h * kD + g * 4);
      float p = q4.x * kv.x + q4.y * kv.y + q4.z * kv.z + q4.w * kv.w;
#pragma unroll
      for (int o = 8; o; o >>= 1) p += __shfl_xor(p, o, 16);
      if (g == 0) logits[bh * kLpad + n] = p;
    }
  }
}

__global__ __launch_bounds__(256) void cls_softmax_k(const float* __restrict__ logits,
                                                     float* __restrict__ pbuf) {
  __shared__ float red[8];
  const int bh = blockIdx.x, tid = threadIdx.x;
  float m = -1e30f;
  for (int n = tid; n < kN; n += 256) m = fmaxf(m, logits[bh * kLpad + n]);
#pragma unroll
  for (int o = 32; o; o >>= 1) m = fmaxf(m, __shfl_xor(m, o));
  if ((tid & 63) == 0) red[tid >> 6] = m;
  __syncthreads();
  m = fmaxf(fmaxf(red[0], red[1]), fmaxf(red[2], red[3]));
  float sum = 0.f;
  for (int n = tid; n < kN; n += 256) sum += __expf(logits[bh * kLpad + n] - m);
#pragma unroll
  for (int o = 32; o; o >>= 1) sum += __shfl_xor(sum, o);
  if ((tid & 63) == 0) red[4 + (tid >> 6)] = sum;
  __syncthreads();
  const float inv = 1.f / (red[4] + red[5] + red[6] + red[7]);
  for (int n = tid; n < kN; n += 256)
    pbuf[bh * kLpad + n] = __expf(logits[bh * kLpad + n] - m) * inv;
}

__global__ __launch_bounds__(256) void cls_pv_k(const float* __restrict__ qkv,
                                                const float* __restrict__ pbuf,
                                                float* __restrict__ partial) {
  __shared__ float pb[256];
  const int chunk = blockIdx.x, bh = blockIdx.y;
  const int b = bh / kH, h = bh % kH;
  const int j = threadIdx.x & 63, part = threadIdx.x >> 6;
  const size_t base = (size_t)b * kN * k3C + 2 * kC + h * kD + j;
  float acc = 0.f;
#pragma unroll 4
  for (int i = 0; i < 64; ++i) {
    const int n = chunk * 256 + i * 4 + part;
    if (n < kN) acc = fmaf(pbuf[bh * kLpad + n], qkv[base + (size_t)n * k3C], acc);
  }
  pb[threadIdx.x] = acc;
  __syncthreads();
  if (part == 0)
    partial[((size_t)bh * 7 + chunk) * kD + j] =
        pb[j] + pb[64 + j] + pb[128 + j] + pb[192 + j];
}

__global__ void cls_red_k(const float* __restrict__ partial,
                          ushort* __restrict__ xin_b) {
  const int bh = blockIdx.x, j = threadIdx.x;
  const int b = bh / kH, h = bh % kH;
  float s = 0.f;
#pragma unroll
  for (int c = 0; c < 7; ++c) s += partial[((size_t)bh * 7 + c) * kD + j];
  xin_b[(size_t)(b * kN) * kC + h * kD + j] = f2bf(s);
}

// ---------- xd gather (bf16 -> bf16) ----------
__global__ void xd_gather_k(const ushort* __restrict__ x4b,
                            ushort* __restrict__ xd_b) {
  const int idx = blockIdx.x * 256 + threadIdx.x;
  const int total = kB * kS * (kC / 8);
  if (idx >= total) return;
  const int row = idx / (kC / 8);
  const int cg = idx - row * (kC / 8);
  const int b = row / kS, s = row - b * kS;
  const int fq = s / kP;
  ((ulonglong2*)xd_b)[(size_t)row * (kC / 8) + cg] =
      ((const ulonglong2*)x4b)[((size_t)(b * kS + s) * kF + fq) * (kC / 8) + cg];
}

// ---------- temporal attn over F=8 ----------
__global__ __launch_bounds__(256) void attn2_k(
    const float* __restrict__ q2, const float* __restrict__ k2,
    const ushort* __restrict__ x4b, ushort* __restrict__ xin_b,
    float* __restrict__ attn2out) {
  const int item = blockIdx.x * 4 + (threadIdx.x >> 6);
  const int lane = threadIdx.x & 63;
  const int s = item % kS;
  const int t = item / kS;
  const int h = t % kH, b = t / kH;
  const float qv = q2[(size_t)(b * kS + s) * kC + h * kD + lane] * kScale;
  float l[kF];
#pragma unroll
  for (int f = 0; f < kF; ++f) {
    float p = qv * k2[((size_t)(b * kS + s) * kF + f) * kC + h * kD + lane];
#pragma unroll
    for (int o = 32; o; o >>= 1) p += __shfl_xor(p, o);
    l[f] = p;
  }
  float m = l[0];
#pragma unroll
  for (int f = 1; f < kF; ++f) m = fmaxf(m, l[f]);
  float sum = 0.f;
#pragma unroll
  for (int f = 0; f < kF; ++f) {
    l[f] = __expf(l[f] - m);
    sum += l[f];
  }
  const float inv = 1.f / sum;
  float o = 0.f;
#pragma unroll
  for (int f = 0; f < kF; ++f)
    o = fmaf(l[f] * inv,
             bf2f(x4b[((size_t)(b * kS + s) * kF + f) * kC + h * kD + lane]), o);
  if (lane < kF)
    attn2out[((size_t)(b * kH + h) * kS + s) * kF + lane] = l[lane] * inv;
  xin_b[(size_t)(b * kN + 1 + s) * kC + h * kD + lane] = f2bf(o);
}

extern "C" void kernel_launch(void* const* d_in, const int* in_sizes, int n_in,
                              void* d_out, int out_size, void* d_ws,
                              size_t ws_size, hipStream_t stream) {
  const float* x = (const float*)d_in[0];
  const float* Wqkv = (const float*)d_in[1];
  const float* Wq = (const float*)d_in[2];
  const float* Wkv = (const float*)d_in[3];
  const float* Wproj = (const float*)d_in[4];
  const float* bproj = (const float*)d_in[5];

  char* p = (char*)d_ws;
  float* qkv = (float*)p;            p += (size_t)3138 * 2304 * 4;
  float* k2 = (float*)p;             p += (size_t)25088 * 768 * 4;
  float* q2 = (float*)p;             p += (size_t)3136 * 768 * 4;
  ushort* x4b = (ushort*)p;          p += (size_t)25088 * 768 * 2;
  ushort* xin_b = (ushort*)p;        p += (size_t)3138 * 768 * 2;
  ushort* xd_b = (ushort*)p;         p += (size_t)3136 * 768 * 2;
  ushort* xb = (ushort*)p;           p += (size_t)3138 * 768 * 2;
  ushort* Wqkv_t = (ushort*)p;       p += (size_t)2304 * 768 * 2;
  ushort* Wq_t = (ushort*)p;         p += (size_t)768 * 768 * 2;
  ushort* Wk_t = (ushort*)p;         p += (size_t)768 * 768 * 2;
  ushort* Wproj_t = (ushort*)p;      p += (size_t)768 * 768 * 2;
  ushort* Qb = (ushort*)p;           p += (size_t)kBH * kS * kD * 2;
  ushort* Kb = (ushort*)p;           p += ((size_t)kBH * kS + 16) * kD * 2;
  ushort* Vt = (ushort*)p;           p += (size_t)kBH * kF * kD * kPpad * 2;
  float* clsL = (float*)p;           p += (size_t)kBH * kLpad * 4;
  float* clsP = (float*)p;           p += (size_t)kBH * kLpad * 4;
  float* clsPart = (float*)p;

  float* out = (float*)d_out;
  float* attn2 = out + (size_t)kB * kN * kC;

  // 0. packs
  pack_x_k<<<(3138 * 768 / 4 + 255) / 256, 256, 0, stream>>>(x, xb, 3138 * 768 / 4);
  pack_wt_k<<<dim3(72, 24), 256, 0, stream>>>(Wqkv, Wqkv_t, 2304);
  pack_wt_k<<<dim3(24, 24), 256, 0, stream>>>(Wq, Wq_t, 768);
  pack_wt_k<<<dim3(24, 24), 256, 0, stream>>>(Wkv, Wk_t, 1536);
  pack_wt_k<<<dim3(24, 24), 256, 0, stream>>>(Wproj, Wproj_t, 768);
  // 1. qkv = x @ Wqkv
  gemm_bf16<<<18 * 25, 256, 0, stream>>>(xb, Wqkv_t, nullptr, qkv, 3138, 2304,
                                         768, 18);
  // 2. pack attention operands
  pack_qk_k<<<(kBH * kS * kD + 255) / 256, 256, 0, stream>>>(qkv, Qb, Kb);
  pack_vt_k<<<(kBH * kF * kD * kPpad + 255) / 256, 256, 0, stream>>>(qkv, Vt);
  // 3. cls attention (4-phase)
  cls_logits_k<<<dim3(7, 24), 256, 0, stream>>>(qkv, clsL);
  cls_softmax_k<<<24, 256, 0, stream>>>(clsL, clsP);
  cls_pv_k<<<dim3(7, 24), 256, 0, stream>>>(qkv, clsP, clsPart);
  cls_red_k<<<24, 64, 0, stream>>>(clsPart, xin_b);
  // 4. spatial attention -> x4b   (XCD-local K/V: grid.x = f*24+bh)
  sp_attn_mfma<<<dim3(192, 25), 128, 0, stream>>>(Qb, Kb, Vt, x4b);
  // 5. xd gather
  xd_gather_k<<<(kB * kS * (kC / 8) + 255) / 256, 256, 0, stream>>>(x4b, xd_b);
  // 6. q2 = xd @ Wq
  gemm_bf16<<<6 * 25, 256, 0, stream>>>(xd_b, Wq_t, nullptr, q2, 3136, 768,
                                        768, 6);
  // 7. k2 = x4 @ Wkv[:, :768]
  gemm_bf16<<<6 * 196, 256, 0, stream>>>(x4b, Wk_t, nullptr, k2, 25088, 768,
                                         768, 6);
  // 8. temporal attention
  attn2_k<<<9408, 256, 0, stream>>>(q2, k2, x4b, xin_b, attn2);
  // 9. out = xin @ Wproj + bproj
  gemm_bf16<<<6 * 25, 256, 0, stream>>>(xin_b, Wproj_t, bproj, out, 3138, 768,
                                        768, 6);
}

// Round 6
// 281.620 us; speedup vs baseline: 5.6396x; 1.0521x over previous
//
#include <hip/hip_runtime.h>

namespace {
constexpr int kB = 2;
constexpr int kH = 12;
constexpr int kD = 64;
constexpr int kC = 768;
constexpr int kF = 8;
constexpr int kP = 196;
constexpr int kS = kF * kP;      // 1568
constexpr int kN = 1 + kS;       // 1569
constexpr int k3C = 3 * kC;      // 2304
constexpr float kScale = 0.125f; // d^-0.5
constexpr int kBH = kB * kH;     // 24
constexpr int kPpad = 224;       // keys padded for PV K-dim (7x32)
constexpr int kLpad = 1600;      // cls logits row stride
}

typedef __attribute__((ext_vector_type(8))) short bf16x8;
typedef __attribute__((ext_vector_type(4))) float f32x4;
typedef __attribute__((ext_vector_type(4))) unsigned int u32x4;

__device__ inline ushort f2bf(float x) {
  union { float f; unsigned u; } v{x};
  unsigned r = v.u + 0x7fff + ((v.u >> 16) & 1);
  return (ushort)(r >> 16);
}
__device__ inline float bf2f(ushort u) {
  union { unsigned u; float f; } v{(unsigned)u << 16};
  return v.f;
}

__device__ __forceinline__ void gload_lds16(const void* g, void* l) {
  __builtin_amdgcn_global_load_lds(
      (const __attribute__((address_space(1))) unsigned int*)g,
      (__attribute__((address_space(3))) unsigned int*)l, 16, 0, 0);
}

__device__ inline void storeC(float v, float* p) { *p = v; }
__device__ inline void storeC(float v, ushort* p) { *p = f2bf(v); }

// ---------- bf16 MFMA GEMM: C[M,N] = A[M,K]bf16 @ Bt[N,K]bf16^T (+bias) ----
// OutT = float or ushort(bf16). 1-D grid, m204-bijective XCD remap.
template <typename OutT>
__global__ __launch_bounds__(256) void gemm_bf16(
    const ushort* __restrict__ A, const ushort* __restrict__ Bt,
    const float* __restrict__ bias, OutT* __restrict__ C,
    int M, int N, int K, int nbx) {
  const int nwg = gridDim.x;
  const int q = nwg >> 3, rr = nwg & 7;
  const int xcd = blockIdx.x & 7, loc = blockIdx.x >> 3;
  const int vid = ((xcd < rr) ? xcd * (q + 1) : rr * (q + 1) + (xcd - rr) * q) + loc;
  const int m0 = (vid / nbx) * 128, n0 = (vid % nbx) * 128;

  __shared__ __align__(16) ushort As[128 * 32];
  __shared__ __align__(16) ushort Bs[128 * 32];
  const int tid = threadIdx.x;
  const int r0 = tid >> 2, c0 = tid & 3;
  const int r1 = r0 + 64;
  const int sc0 = (c0 ^ ((r0 >> 1) & 3)) * 8;
  const int sc1 = (c0 ^ ((r1 >> 1) & 3)) * 8;
  const int ar0 = min(m0 + r0, M - 1), ar1 = min(m0 + r1, M - 1);
  const ushort* ga0 = A + (size_t)ar0 * K + sc0;
  const ushort* ga1 = A + (size_t)ar1 * K + sc1;
  const ushort* gb0 = Bt + (size_t)(n0 + r0) * K + sc0;
  const ushort* gb1 = Bt + (size_t)(n0 + r1) * K + sc1;
  const int w = tid >> 6;
  char* lA0 = (char*)As + w * 1024;
  char* lA1 = (char*)As + 4096 + w * 1024;
  char* lB0 = (char*)Bs + w * 1024;
  char* lB1 = (char*)Bs + 4096 + w * 1024;
  const int lane = tid & 63;
  const int lr = lane & 15, lg = lane >> 4;
  const int wr = w >> 1, wc = w & 1;
  f32x4 acc[4][4] = {};
  for (int kt = 0; kt < K; kt += 32) {
    gload_lds16(ga0 + kt, lA0);
    gload_lds16(ga1 + kt, lA1);
    gload_lds16(gb0 + kt, lB0);
    gload_lds16(gb1 + kt, lB1);
    __syncthreads();
    bf16x8 af[4], bfr[4];
#pragma unroll
    for (int m = 0; m < 4; ++m) {
      int row = wr * 64 + m * 16 + lr;
      int ch = lg ^ ((row >> 1) & 3);
      af[m] = *(const bf16x8*)(As + row * 32 + ch * 8);
    }
#pragma unroll
    for (int n = 0; n < 4; ++n) {
      int row = wc * 64 + n * 16 + lr;
      int ch = lg ^ ((row >> 1) & 3);
      bfr[n] = *(const bf16x8*)(Bs + row * 32 + ch * 8);
    }
#pragma unroll
    for (int m = 0; m < 4; ++m)
#pragma unroll
      for (int n = 0; n < 4; ++n)
        acc[m][n] =
            __builtin_amdgcn_mfma_f32_16x16x32_bf16(af[m], bfr[n], acc[m][n], 0, 0, 0);
    __syncthreads();
  }
#pragma unroll
  for (int m = 0; m < 4; ++m) {
#pragma unroll
    for (int r = 0; r < 4; ++r) {
      const int mg = m0 + wr * 64 + m * 16 + lg * 4 + r;
      if (mg < M) {
        OutT* crow = C + (size_t)mg * N + n0 + wc * 64 + lr;
#pragma unroll
        for (int n = 0; n < 4; ++n) {
          float v = acc[m][n][r];
          if (bias) v += bias[n0 + wc * 64 + n * 16 + lr];
          storeC(v, crow + n * 16);
        }
      }
    }
  }
}

// ---------- pack x -> bf16 ----------
__global__ void pack_x_k(const float* __restrict__ X, ushort* __restrict__ Xb,
                         int n4) {
  const int i = blockIdx.x * 256 + threadIdx.x;
  if (i >= n4) return;
  float4 v = ((const float4*)X)[i];
  ushort4 o = {f2bf(v.x), f2bf(v.y), f2bf(v.z), f2bf(v.w)};
  ((ushort4*)Xb)[i] = o;
}

// ---------- pack W[768][ldw] cols[0,Ncols) -> Wt[Ncols][768] bf16 ----------
__global__ __launch_bounds__(256) void pack_wt_k(const float* __restrict__ W,
                                                 ushort* __restrict__ Wt,
                                                 int ldw) {
  __shared__ float t[32][33];
  const int nb = blockIdx.x * 32;
  const int kb = blockIdx.y * 32;
  const int tx = threadIdx.x & 31, ty = threadIdx.x >> 5;
#pragma unroll
  for (int i = 0; i < 32; i += 8)
    t[ty + i][tx] = W[(size_t)(kb + ty + i) * ldw + nb + tx];
  __syncthreads();
#pragma unroll
  for (int i = 0; i < 32; i += 8)
    Wt[(size_t)(nb + ty + i) * 768 + kb + tx] = f2bf(t[tx][ty + i]);
}

// ---------- pack q,k (scaled q) into bf16 row-major [bh][1568][64] ----------
__global__ void pack_qk_k(const float* __restrict__ qkv, ushort* __restrict__ Qb,
                          ushort* __restrict__ Kb) {
  const int idx = blockIdx.x * 256 + threadIdx.x;
  if (idx >= kBH * kS * kD) return;
  const int j = idx & 63;
  const int s = (idx >> 6) % kS;
  const int bh = idx / (kS * kD);
  const int b = bh / kH, h = bh % kH;
  const size_t src = (size_t)(b * kN + 1 + s) * k3C + h * kD + j;
  Qb[idx] = f2bf(qkv[src] * kScale);
  Kb[idx] = f2bf(qkv[src + kC]);
}

// ---------- pack V transposed: Vt[bh*8+f][64][224] bf16 ----------
__global__ void pack_vt_k(const float* __restrict__ qkv, ushort* __restrict__ Vt) {
  const int idx = blockIdx.x * 256 + threadIdx.x;
  if (idx >= kBH * kF * kD * kPpad) return;
  const int n = idx % kPpad;
  const int j = (idx / kPpad) & 63;
  const int f = (idx / (kPpad * kD)) & 7;
  const int bh = idx / (kPpad * kD * kF);
  const int b = bh / kH, h = bh % kH;
  float v = 0.f;
  if (n < kP)
    v = qkv[(size_t)(b * kN + 1 + f * kP + n) * k3C + 2 * kC + h * kD + j];
  Vt[idx] = f2bf(v);
}

// ---------- spatial attention, swapped-QK^T, LDS-free ----------
// grid (192 = f*24+bh, 13), 4 waves/block, each wave = one 32-query tile.
// S^T = mfma(K,Q): lane owns query lr; P packed bf16 in-reg, redistributed
// C/D->B-frag via bpermute; O^T = mfma(V^T, P^T); zero LDS, zero barriers.
__global__ __launch_bounds__(256) void sp_attn_mfma(
    const ushort* __restrict__ Qb, const ushort* __restrict__ Kb,
    const ushort* __restrict__ Vt, ushort* __restrict__ x4b) {
  const int w = threadIdx.x >> 6;
  const int lane = threadIdx.x & 63;
  const int fbh = blockIdx.x;
  const int f = fbh / 24, bh = fbh % 24;
  const int tile = blockIdx.y * 4 + w;  // 0..48 valid
  if (tile >= 49) return;
  const int q0 = tile * 32;
  const int lr = lane & 15;
  const int lg = lane >> 4;

  // Q fragments (used as B operand -> output cols = queries)
  const ushort* qrow = Qb + ((size_t)bh * kS + q0 + lr) * kD + lg * 8;
  const bf16x8 a00 = *(const bf16x8*)qrow;
  const bf16x8 a01 = *(const bf16x8*)(qrow + 32);
  const bf16x8 a10 = *(const bf16x8*)(qrow + 16 * kD);
  const bf16x8 a11 = *(const bf16x8*)(qrow + 16 * kD + 32);

  // S^T[key][q]: key = nt*16 + lg*4 + r, q = lr (half0) / 16+lr (half1)
  f32x4 s0[13], s1[13];
  const ushort* kbase = Kb + ((size_t)bh * kS + f * kP + lr) * kD + lg * 8;
#pragma unroll
  for (int nt = 0; nt < 13; ++nt) {
    const ushort* kr = kbase + (size_t)nt * 16 * kD;
    bf16x8 b0 = *(const bf16x8*)kr;
    bf16x8 b1 = *(const bf16x8*)(kr + 32);
    f32x4 acc0 = {0.f, 0.f, 0.f, 0.f}, acc1 = {0.f, 0.f, 0.f, 0.f};
    acc0 = __builtin_amdgcn_mfma_f32_16x16x32_bf16(b0, a00, acc0, 0, 0, 0);
    acc0 = __builtin_amdgcn_mfma_f32_16x16x32_bf16(b1, a01, acc0, 0, 0, 0);
    acc1 = __builtin_amdgcn_mfma_f32_16x16x32_bf16(b0, a10, acc1, 0, 0, 0);
    acc1 = __builtin_amdgcn_mfma_f32_16x16x32_bf16(b1, a11, acc1, 0, 0, 0);
    s0[nt] = acc0;
    s1[nt] = acc1;
  }
  // tile 12 holds keys 192..207; keys >=196 are output rows lg>=1
  if (lg >= 1) {
#pragma unroll
    for (int r = 0; r < 4; ++r) { s0[12][r] = -1e30f; s1[12][r] = -1e30f; }
  }

  // per-query max: own 52 regs + butterfly over the 4 stride-16 lanes
  float m0 = -1e30f, m1 = -1e30f;
#pragma unroll
  for (int nt = 0; nt < 13; ++nt)
#pragma unroll
    for (int r = 0; r < 4; ++r) {
      m0 = fmaxf(m0, s0[nt][r]);
      m1 = fmaxf(m1, s1[nt][r]);
    }
  m0 = fmaxf(m0, __shfl_xor(m0, 16));
  m0 = fmaxf(m0, __shfl_xor(m0, 32));
  m1 = fmaxf(m1, __shfl_xor(m1, 16));
  m1 = fmaxf(m1, __shfl_xor(m1, 32));

  // exp -> bf16 pairs -> redistribute C/D layout -> B-frag layout.
  // target (lg,j2) <- tile (lg>>1), src group (lg&1)*2+(j2>>1), pk (j2&1)
  float sum0 = 0.f, sum1 = 0.f;
  u32x4 breg0[7], breg1[7];
#pragma unroll
  for (int blk = 0; blk < 7; ++blk) {
    unsigned pk0[2][2], pk1[2][2];
#pragma unroll
    for (int t = 0; t < 2; ++t) {
      const int nt = blk * 2 + t;
      if (nt < 13) {
        float e0 = __expf(s0[nt][0] - m0), e1 = __expf(s0[nt][1] - m0);
        float e2 = __expf(s0[nt][2] - m0), e3 = __expf(s0[nt][3] - m0);
        sum0 += (e0 + e1) + (e2 + e3);
        pk0[t][0] = ((unsigned)f2bf(e1) << 16) | f2bf(e0);
        pk0[t][1] = ((unsigned)f2bf(e3) << 16) | f2bf(e2);
        float g0 = __expf(s1[nt][0] - m1), g1 = __expf(s1[nt][1] - m1);
        float g2 = __expf(s1[nt][2] - m1), g3 = __expf(s1[nt][3] - m1);
        sum1 += (g0 + g1) + (g2 + g3);
        pk1[t][0] = ((unsigned)f2bf(g1) << 16) | f2bf(g0);
        pk1[t][1] = ((unsigned)f2bf(g3) << 16) | f2bf(g2);
      } else {
        pk0[t][0] = 0; pk0[t][1] = 0;
        pk1[t][0] = 0; pk1[t][1] = 0;
      }
    }
#pragma unroll
    for (int j2 = 0; j2 < 4; ++j2) {
      const int srcLane = ((lg & 1) * 2 + (j2 >> 1)) * 16 + lr;
      unsigned t0 = (unsigned)__shfl((int)pk0[0][j2 & 1], srcLane);
      unsigned t1 = (unsigned)__shfl((int)pk0[1][j2 & 1], srcLane);
      breg0[blk][j2] = (lg < 2) ? t0 : t1;
      unsigned u0 = (unsigned)__shfl((int)pk1[0][j2 & 1], srcLane);
      unsigned u1 = (unsigned)__shfl((int)pk1[1][j2 & 1], srcLane);
      breg1[blk][j2] = (lg < 2) ? u0 : u1;
    }
  }
  sum0 += __shfl_xor(sum0, 16);
  sum0 += __shfl_xor(sum0, 32);
  sum1 += __shfl_xor(sum1, 16);
  sum1 += __shfl_xor(sum1, 32);
  const float inv0 = 1.f / sum0, inv1 = 1.f / sum1;

  // O^T = V^T @ P^T : A = Vt rows (d), B = P^T. Lane ends with q=lr,
  // d = nt2*16 + lg*4 + r  -> 4 consecutive d per reg -> 8B stores.
  const ushort* vbase = Vt + ((size_t)(bh * kF + f) * kD + lr) * kPpad + lg * 8;
  f32x4 o0[4] = {}, o1[4] = {};
#pragma unroll
  for (int nt2 = 0; nt2 < 4; ++nt2) {
    const ushort* vb = vbase + (size_t)nt2 * 16 * kPpad;
#pragma unroll
    for (int blk = 0; blk < 7; ++blk) {
      bf16x8 av = *(const bf16x8*)(vb + blk * 32);
      bf16x8 pb0 = __builtin_bit_cast(bf16x8, breg0[blk]);
      bf16x8 pb1 = __builtin_bit_cast(bf16x8, breg1[blk]);
      o0[nt2] = __builtin_amdgcn_mfma_f32_16x16x32_bf16(av, pb0, o0[nt2], 0, 0, 0);
      o1[nt2] = __builtin_amdgcn_mfma_f32_16x16x32_bf16(av, pb1, o1[nt2], 0, 0, 0);
    }
  }

  const int b = bh / kH, h = bh % kH;
  const size_t base0 =
      ((size_t)(b * kS + q0 + lr) * kF + f) * kC + h * kD + lg * 4;
#pragma unroll
  for (int nt2 = 0; nt2 < 4; ++nt2) {
    ushort4 v0, v1;
    v0.x = f2bf(o0[nt2][0] * inv0);
    v0.y = f2bf(o0[nt2][1] * inv0);
    v0.z = f2bf(o0[nt2][2] * inv0);
    v0.w = f2bf(o0[nt2][3] * inv0);
    *(ushort4*)(x4b + base0 + nt2 * 16) = v0;
    v1.x = f2bf(o1[nt2][0] * inv1);
    v1.y = f2bf(o1[nt2][1] * inv1);
    v1.z = f2bf(o1[nt2][2] * inv1);
    v1.w = f2bf(o1[nt2][3] * inv1);
    *(ushort4*)(x4b + base0 + (size_t)16 * kF * kC + nt2 * 16) = v1;
  }
}

// ---------- cls attention, 4-phase parallel ----------
__global__ __launch_bounds__(256) void cls_logits_k(const float* __restrict__ qkv,
                                                    float* __restrict__ logits) {
  const int chunk = blockIdx.x, bh = blockIdx.y;
  const int b = bh / kH, h = bh % kH;
  const int g = threadIdx.x & 15, row = threadIdx.x >> 4;
  const size_t base = (size_t)b * kN * k3C;
  float4 q4 = *(const float4*)(qkv + base + h * kD + g * 4);
  q4.x *= kScale; q4.y *= kScale; q4.z *= kScale; q4.w *= kScale;
#pragma unroll
  for (int i = 0; i < 16; ++i) {
    const int n = chunk * 256 + i * 16 + row;
    if (n < kN) {
      const float4 kv =
          *(const float4*)(qkv + base + (size_t)n * k3C + kC + h * kD + g * 4);
      float p = q4.x * kv.x + q4.y * kv.y + q4.z * kv.z + q4.w * kv.w;
#pragma unroll
      for (int o = 8; o; o >>= 1) p += __shfl_xor(p, o, 16);
      if (g == 0) logits[bh * kLpad + n] = p;
    }
  }
}

__global__ __launch_bounds__(256) void cls_softmax_k(const float* __restrict__ logits,
                                                     float* __restrict__ pbuf) {
  __shared__ float red[8];
  const int bh = blockIdx.x, tid = threadIdx.x;
  float m = -1e30f;
  for (int n = tid; n < kN; n += 256) m = fmaxf(m, logits[bh * kLpad + n]);
#pragma unroll
  for (int o = 32; o; o >>= 1) m = fmaxf(m, __shfl_xor(m, o));
  if ((tid & 63) == 0) red[tid >> 6] = m;
  __syncthreads();
  m = fmaxf(fmaxf(red[0], red[1]), fmaxf(red[2], red[3]));
  float sum = 0.f;
  for (int n = tid; n < kN; n += 256) sum += __expf(logits[bh * kLpad + n] - m);
#pragma unroll
  for (int o = 32; o; o >>= 1) sum += __shfl_xor(sum, o);
  if ((tid & 63) == 0) red[4 + (tid >> 6)] = sum;
  __syncthreads();
  const float inv = 1.f / (red[4] + red[5] + red[6] + red[7]);
  for (int n = tid; n < kN; n += 256)
    pbuf[bh * kLpad + n] = __expf(logits[bh * kLpad + n] - m) * inv;
}

__global__ __launch_bounds__(256) void cls_pv_k(const float* __restrict__ qkv,
                                                const float* __restrict__ pbuf,
                                                float* __restrict__ partial) {
  __shared__ float pb[256];
  const int chunk = blockIdx.x, bh = blockIdx.y;
  const int b = bh / kH, h = bh % kH;
  const int j = threadIdx.x & 63, part = threadIdx.x >> 6;
  const size_t base = (size_t)b * kN * k3C + 2 * kC + h * kD + j;
  float acc = 0.f;
#pragma unroll 4
  for (int i = 0; i < 64; ++i) {
    const int n = chunk * 256 + i * 4 + part;
    if (n < kN) acc = fmaf(pbuf[bh * kLpad + n], qkv[base + (size_t)n * k3C], acc);
  }
  pb[threadIdx.x] = acc;
  __syncthreads();
  if (part == 0)
    partial[((size_t)bh * 7 + chunk) * kD + j] =
        pb[j] + pb[64 + j] + pb[128 + j] + pb[192 + j];
}

__global__ void cls_red_k(const float* __restrict__ partial,
                          ushort* __restrict__ xin_b) {
  const int bh = blockIdx.x, j = threadIdx.x;
  const int b = bh / kH, h = bh % kH;
  float s = 0.f;
#pragma unroll
  for (int c = 0; c < 7; ++c) s += partial[((size_t)bh * 7 + c) * kD + j];
  xin_b[(size_t)(b * kN) * kC + h * kD + j] = f2bf(s);
}

// ---------- xd gather (bf16 -> bf16) ----------
__global__ void xd_gather_k(const ushort* __restrict__ x4b,
                            ushort* __restrict__ xd_b) {
  const int idx = blockIdx.x * 256 + threadIdx.x;
  const int total = kB * kS * (kC / 8);
  if (idx >= total) return;
  const int row = idx / (kC / 8);
  const int cg = idx - row * (kC / 8);
  const int b = row / kS, s = row - b * kS;
  const int fq = s / kP;
  ((ulonglong2*)xd_b)[(size_t)row * (kC / 8) + cg] =
      ((const ulonglong2*)x4b)[((size_t)(b * kS + s) * kF + fq) * (kC / 8) + cg];
}

// ---------- temporal attn over F=8 (bf16 q2/k2/x4) ----------
__global__ __launch_bounds__(256) void attn2_k(
    const ushort* __restrict__ q2b, const ushort* __restrict__ k2b,
    const ushort* __restrict__ x4b, ushort* __restrict__ xin_b,
    float* __restrict__ attn2out) {
  const int item = blockIdx.x * 4 + (threadIdx.x >> 6);
  const int lane = threadIdx.x & 63;
  const int s = item % kS;
  const int t = item / kS;
  const int h = t % kH, b = t / kH;
  const float qv = bf2f(q2b[(size_t)(b * kS + s) * kC + h * kD + lane]) * kScale;
  float l[kF];
#pragma unroll
  for (int f = 0; f < kF; ++f) {
    float p = qv * bf2f(k2b[((size_t)(b * kS + s) * kF + f) * kC + h * kD + lane]);
#pragma unroll
    for (int o = 32; o; o >>= 1) p += __shfl_xor(p, o);
    l[f] = p;
  }
  float m = l[0];
#pragma unroll
  for (int f = 1; f < kF; ++f) m = fmaxf(m, l[f]);
  float sum = 0.f;
#pragma unroll
  for (int f = 0; f < kF; ++f) {
    l[f] = __expf(l[f] - m);
    sum += l[f];
  }
  const float inv = 1.f / sum;
  float o = 0.f;
#pragma unroll
  for (int f = 0; f < kF; ++f)
    o = fmaf(l[f] * inv,
             bf2f(x4b[((size_t)(b * kS + s) * kF + f) * kC + h * kD + lane]), o);
  if (lane < kF)
    attn2out[((size_t)(b * kH + h) * kS + s) * kF + lane] = l[lane] * inv;
  xin_b[(size_t)(b * kN + 1 + s) * kC + h * kD + lane] = f2bf(o);
}

extern "C" void kernel_launch(void* const* d_in, const int* in_sizes, int n_in,
                              void* d_out, int out_size, void* d_ws,
                              size_t ws_size, hipStream_t stream) {
  const float* x = (const float*)d_in[0];
  const float* Wqkv = (const float*)d_in[1];
  const float* Wq = (const float*)d_in[2];
  const float* Wkv = (const float*)d_in[3];
  const float* Wproj = (const float*)d_in[4];
  const float* bproj = (const float*)d_in[5];

  char* p = (char*)d_ws;
  float* qkv = (float*)p;            p += (size_t)3138 * 2304 * 4;
  ushort* k2b = (ushort*)p;          p += (size_t)25088 * 768 * 2;
  ushort* q2b = (ushort*)p;          p += (size_t)3136 * 768 * 2;
  ushort* x4b = (ushort*)p;          p += (size_t)25088 * 768 * 2;
  ushort* xin_b = (ushort*)p;        p += (size_t)3138 * 768 * 2;
  ushort* xd_b = (ushort*)p;         p += (size_t)3136 * 768 * 2;
  ushort* xb = (ushort*)p;           p += (size_t)3138 * 768 * 2;
  ushort* Wqkv_t = (ushort*)p;       p += (size_t)2304 * 768 * 2;
  ushort* Wq_t = (ushort*)p;         p += (size_t)768 * 768 * 2;
  ushort* Wk_t = (ushort*)p;         p += (size_t)768 * 768 * 2;
  ushort* Wproj_t = (ushort*)p;      p += (size_t)768 * 768 * 2;
  ushort* Qb = (ushort*)p;           p += (size_t)kBH * kS * kD * 2;
  ushort* Kb = (ushort*)p;           p += ((size_t)kBH * kS + 16) * kD * 2;
  ushort* Vt = (ushort*)p;           p += (size_t)kBH * kF * kD * kPpad * 2;
  float* clsL = (float*)p;           p += (size_t)kBH * kLpad * 4;
  float* clsP = (float*)p;           p += (size_t)kBH * kLpad * 4;
  float* clsPart = (float*)p;

  float* out = (float*)d_out;
  float* attn2 = out + (size_t)kB * kN * kC;

  // 0. packs
  pack_x_k<<<(3138 * 768 / 4 + 255) / 256, 256, 0, stream>>>(x, xb, 3138 * 768 / 4);
  pack_wt_k<<<dim3(72, 24), 256, 0, stream>>>(Wqkv, Wqkv_t, 2304);
  pack_wt_k<<<dim3(24, 24), 256, 0, stream>>>(Wq, Wq_t, 768);
  pack_wt_k<<<dim3(24, 24), 256, 0, stream>>>(Wkv, Wk_t, 1536);
  pack_wt_k<<<dim3(24, 24), 256, 0, stream>>>(Wproj, Wproj_t, 768);
  // 1. qkv = x @ Wqkv (fp32 out, feeds cls + packs)
  gemm_bf16<float><<<18 * 25, 256, 0, stream>>>(xb, Wqkv_t, nullptr, qkv, 3138,
                                                2304, 768, 18);
  // 2. pack attention operands
  pack_qk_k<<<(kBH * kS * kD + 255) / 256, 256, 0, stream>>>(qkv, Qb, Kb);
  pack_vt_k<<<(kBH * kF * kD * kPpad + 255) / 256, 256, 0, stream>>>(qkv, Vt);
  // 3. cls attention (4-phase)
  cls_logits_k<<<dim3(7, 24), 256, 0, stream>>>(qkv, clsL);
  cls_softmax_k<<<24, 256, 0, stream>>>(clsL, clsP);
  cls_pv_k<<<dim3(7, 24), 256, 0, stream>>>(qkv, clsP, clsPart);
  cls_red_k<<<24, 64, 0, stream>>>(clsPart, xin_b);
  // 4. spatial attention -> x4b (LDS-free, XCD-local via grid.x = f*24+bh)
  sp_attn_mfma<<<dim3(192, 13), 256, 0, stream>>>(Qb, Kb, Vt, x4b);
  // 5. xd gather
  xd_gather_k<<<(kB * kS * (kC / 8) + 255) / 256, 256, 0, stream>>>(x4b, xd_b);
  // 6. q2 = xd @ Wq (bf16 out)
  gemm_bf16<ushort><<<6 * 25, 256, 0, stream>>>(xd_b, Wq_t, nullptr, q2b, 3136,
                                                768, 768, 6);
  // 7. k2 = x4 @ Wkv[:, :768] (bf16 out)
  gemm_bf16<ushort><<<6 * 196, 256, 0, stream>>>(x4b, Wk_t, nullptr, k2b, 25088,
                                                 768, 768, 6);
  // 8. temporal attention
  attn2_k<<<9408, 256, 0, stream>>>(q2b, k2b, x4b, xin_b, attn2);
  // 9. out = xin @ Wproj + bproj (fp32 out)
  gemm_bf16<float><<<6 * 25, 256, 0, stream>>>(xin_b, Wproj_t, bproj, out, 3138,
                                               768, 768, 6);
}

// Round 7
// 266.743 us; speedup vs baseline: 5.9541x; 1.0558x over previous
//
#include <hip/hip_runtime.h>

namespace {
constexpr int kB = 2;
constexpr int kH = 12;
constexpr int kD = 64;
constexpr int kC = 768;
constexpr int kF = 8;
constexpr int kP = 196;
constexpr int kS = kF * kP;      // 1568
constexpr int kN = 1 + kS;       // 1569
constexpr int k3C = 3 * kC;      // 2304
constexpr float kScale = 0.125f; // d^-0.5 (exact power of 2)
constexpr int kBH = kB * kH;     // 24
constexpr int kPpad = 224;       // keys padded for PV K-dim (7x32)
constexpr int kLpad = 1600;      // cls logits row stride
constexpr int kBS = kB * kS;     // 3136
}

typedef __attribute__((ext_vector_type(8))) short bf16x8;
typedef __attribute__((ext_vector_type(4))) float f32x4;
typedef __attribute__((ext_vector_type(4))) unsigned int u32x4;

__device__ inline ushort f2bf(float x) {
  union { float f; unsigned u; } v{x};
  unsigned r = v.u + 0x7fff + ((v.u >> 16) & 1);
  return (ushort)(r >> 16);
}
__device__ inline float bf2f(ushort u) {
  union { unsigned u; float f; } v{(unsigned)u << 16};
  return v.f;
}

__device__ __forceinline__ void gload_lds16(const void* g, void* l) {
  __builtin_amdgcn_global_load_lds(
      (const __attribute__((address_space(1))) unsigned int*)g,
      (__attribute__((address_space(3))) unsigned int*)l, 16, 0, 0);
}

__device__ inline void storeC(float v, float* p) { *p = v; }
__device__ inline void storeC(float v, ushort* p) { *p = f2bf(v); }

// ---------- bf16 MFMA GEMM: C[M,N] = A[M,K]bf16 @ Bt[N,K]bf16^T (+bias) ----
template <typename OutT>
__global__ __launch_bounds__(256) void gemm_bf16(
    const ushort* __restrict__ A, const ushort* __restrict__ Bt,
    const float* __restrict__ bias, OutT* __restrict__ C,
    int M, int N, int K, int nbx) {
  const int nwg = gridDim.x;
  const int q = nwg >> 3, rr = nwg & 7;
  const int xcd = blockIdx.x & 7, loc = blockIdx.x >> 3;
  const int vid = ((xcd < rr) ? xcd * (q + 1) : rr * (q + 1) + (xcd - rr) * q) + loc;
  const int m0 = (vid / nbx) * 128, n0 = (vid % nbx) * 128;

  __shared__ __align__(16) ushort As[128 * 32];
  __shared__ __align__(16) ushort Bs[128 * 32];
  const int tid = threadIdx.x;
  const int r0 = tid >> 2, c0 = tid & 3;
  const int r1 = r0 + 64;
  const int sc0 = (c0 ^ ((r0 >> 1) & 3)) * 8;
  const int sc1 = (c0 ^ ((r1 >> 1) & 3)) * 8;
  const int ar0 = min(m0 + r0, M - 1), ar1 = min(m0 + r1, M - 1);
  const ushort* ga0 = A + (size_t)ar0 * K + sc0;
  const ushort* ga1 = A + (size_t)ar1 * K + sc1;
  const ushort* gb0 = Bt + (size_t)(n0 + r0) * K + sc0;
  const ushort* gb1 = Bt + (size_t)(n0 + r1) * K + sc1;
  const int w = tid >> 6;
  char* lA0 = (char*)As + w * 1024;
  char* lA1 = (char*)As + 4096 + w * 1024;
  char* lB0 = (char*)Bs + w * 1024;
  char* lB1 = (char*)Bs + 4096 + w * 1024;
  const int lane = tid & 63;
  const int lr = lane & 15, lg = lane >> 4;
  const int wr = w >> 1, wc = w & 1;
  f32x4 acc[4][4] = {};
  for (int kt = 0; kt < K; kt += 32) {
    gload_lds16(ga0 + kt, lA0);
    gload_lds16(ga1 + kt, lA1);
    gload_lds16(gb0 + kt, lB0);
    gload_lds16(gb1 + kt, lB1);
    __syncthreads();
    bf16x8 af[4], bfr[4];
#pragma unroll
    for (int m = 0; m < 4; ++m) {
      int row = wr * 64 + m * 16 + lr;
      int ch = lg ^ ((row >> 1) & 3);
      af[m] = *(const bf16x8*)(As + row * 32 + ch * 8);
    }
#pragma unroll
    for (int n = 0; n < 4; ++n) {
      int row = wc * 64 + n * 16 + lr;
      int ch = lg ^ ((row >> 1) & 3);
      bfr[n] = *(const bf16x8*)(Bs + row * 32 + ch * 8);
    }
#pragma unroll
    for (int m = 0; m < 4; ++m)
#pragma unroll
      for (int n = 0; n < 4; ++n)
        acc[m][n] =
            __builtin_amdgcn_mfma_f32_16x16x32_bf16(af[m], bfr[n], acc[m][n], 0, 0, 0);
    __syncthreads();
  }
#pragma unroll
  for (int m = 0; m < 4; ++m) {
#pragma unroll
    for (int r = 0; r < 4; ++r) {
      const int mg = m0 + wr * 64 + m * 16 + lg * 4 + r;
      if (mg < M) {
        OutT* crow = C + (size_t)mg * N + n0 + wc * 64 + lr;
#pragma unroll
        for (int n = 0; n < 4; ++n) {
          float v = acc[m][n][r];
          if (bias) v += bias[n0 + wc * 64 + n * 16 + lr];
          storeC(v, crow + n * 16);
        }
      }
    }
  }
}

// ---------- w2[bs][h][c] = sum_d q2b[bs][h*64+d] * Wkvb[c][h*64+d] ----------
// M=3136 (bs), N=768 (c), K=64 per h. grid 1800 = 12h * 25mt * 6nt.
__global__ __launch_bounds__(256) void w2_gemm(
    const ushort* __restrict__ q2b, const ushort* __restrict__ Wkvb,
    ushort* __restrict__ w2b) {
  const int nwg = gridDim.x;
  const int q = nwg >> 3, rr = nwg & 7;
  const int xcd = blockIdx.x & 7, loc = blockIdx.x >> 3;
  const int vid = ((xcd < rr) ? xcd * (q + 1) : rr * (q + 1) + (xcd - rr) * q) + loc;
  const int h = vid / 150;
  const int rem = vid - h * 150;
  const int m0 = (rem / 6) * 128, n0 = (rem % 6) * 128;

  __shared__ __align__(16) ushort As[128 * 32];
  __shared__ __align__(16) ushort Bs[128 * 32];
  const int tid = threadIdx.x;
  const int r0 = tid >> 2, c0 = tid & 3;
  const int r1 = r0 + 64;
  const int sc0 = (c0 ^ ((r0 >> 1) & 3)) * 8;
  const int sc1 = (c0 ^ ((r1 >> 1) & 3)) * 8;
  const int ar0 = min(m0 + r0, kBS - 1), ar1 = min(m0 + r1, kBS - 1);
  const ushort* ga0 = q2b + (size_t)ar0 * kC + h * 64 + sc0;
  const ushort* ga1 = q2b + (size_t)ar1 * kC + h * 64 + sc1;
  const ushort* gb0 = Wkvb + (size_t)(n0 + r0) * kC + h * 64 + sc0;
  const ushort* gb1 = Wkvb + (size_t)(n0 + r1) * kC + h * 64 + sc1;
  const int w = tid >> 6;
  char* lA0 = (char*)As + w * 1024;
  char* lA1 = (char*)As + 4096 + w * 1024;
  char* lB0 = (char*)Bs + w * 1024;
  char* lB1 = (char*)Bs + 4096 + w * 1024;
  const int lane = tid & 63;
  const int lr = lane & 15, lg = lane >> 4;
  const int wr = w >> 1, wc = w & 1;
  f32x4 acc[4][4] = {};
#pragma unroll
  for (int kt = 0; kt < 64; kt += 32) {
    gload_lds16(ga0 + kt, lA0);
    gload_lds16(ga1 + kt, lA1);
    gload_lds16(gb0 + kt, lB0);
    gload_lds16(gb1 + kt, lB1);
    __syncthreads();
    bf16x8 af[4], bfr[4];
#pragma unroll
    for (int m = 0; m < 4; ++m) {
      int row = wr * 64 + m * 16 + lr;
      int ch = lg ^ ((row >> 1) & 3);
      af[m] = *(const bf16x8*)(As + row * 32 + ch * 8);
    }
#pragma unroll
    for (int n = 0; n < 4; ++n) {
      int row = wc * 64 + n * 16 + lr;
      int ch = lg ^ ((row >> 1) & 3);
      bfr[n] = *(const bf16x8*)(Bs + row * 32 + ch * 8);
    }
#pragma unroll
    for (int m = 0; m < 4; ++m)
#pragma unroll
      for (int n = 0; n < 4; ++n)
        acc[m][n] =
            __builtin_amdgcn_mfma_f32_16x16x32_bf16(af[m], bfr[n], acc[m][n], 0, 0, 0);
    __syncthreads();
  }
#pragma unroll
  for (int m = 0; m < 4; ++m) {
#pragma unroll
    for (int r = 0; r < 4; ++r) {
      const int mg = m0 + wr * 64 + m * 16 + lg * 4 + r;
      if (mg < kBS) {
        ushort* crow = w2b + (size_t)mg * (kH * kC) + h * kC + n0 + wc * 64 + lr;
#pragma unroll
        for (int n = 0; n < 4; ++n) crow[n * 16] = f2bf(acc[m][n][r]);
      }
    }
  }
}

// ---------- pack x -> bf16 ----------
__global__ void pack_x_k(const float* __restrict__ X, ushort* __restrict__ Xb,
                         int n4) {
  const int i = blockIdx.x * 256 + threadIdx.x;
  if (i >= n4) return;
  float4 v = ((const float4*)X)[i];
  ushort4 o = {f2bf(v.x), f2bf(v.y), f2bf(v.z), f2bf(v.w)};
  ((ushort4*)Xb)[i] = o;
}

// ---------- pack W[768][ldw] cols[0,Ncols) -> Wt[Ncols][768] bf16 (xscale) ----
__global__ __launch_bounds__(256) void pack_wt_k(const float* __restrict__ W,
                                                 ushort* __restrict__ Wt,
                                                 int ldw, float scale) {
  __shared__ float t[32][33];
  const int nb = blockIdx.x * 32;
  const int kb = blockIdx.y * 32;
  const int tx = threadIdx.x & 31, ty = threadIdx.x >> 5;
#pragma unroll
  for (int i = 0; i < 32; i += 8)
    t[ty + i][tx] = W[(size_t)(kb + ty + i) * ldw + nb + tx];
  __syncthreads();
#pragma unroll
  for (int i = 0; i < 32; i += 8)
    Wt[(size_t)(nb + ty + i) * 768 + kb + tx] = f2bf(t[tx][ty + i] * scale);
}

// ---------- pack Wkv[:, :768] -> Wkvb[768][768] bf16 (no transpose) ----------
__global__ void pack_wkv_k(const float* __restrict__ Wkv,
                           ushort* __restrict__ Wkvb) {
  const int i = blockIdx.x * 256 + threadIdx.x;  // over 768*192 float4s
  if (i >= 768 * 192) return;
  const int c = i / 192, j4 = i - c * 192;
  float4 v = *(const float4*)(Wkv + (size_t)c * 1536 + j4 * 4);
  ushort4 o = {f2bf(v.x), f2bf(v.y), f2bf(v.z), f2bf(v.w)};
  *(ushort4*)(Wkvb + (size_t)c * 768 + j4 * 4) = o;
}

// ---------- pack q,k (scaled q) into bf16 row-major [bh][1568][64] ----------
__global__ void pack_qk_k(const float* __restrict__ qkv, ushort* __restrict__ Qb,
                          ushort* __restrict__ Kb) {
  const int idx = blockIdx.x * 256 + threadIdx.x;
  if (idx >= kBH * kS * kD) return;
  const int j = idx & 63;
  const int s = (idx >> 6) % kS;
  const int bh = idx / (kS * kD);
  const int b = bh / kH, h = bh % kH;
  const size_t src = (size_t)(b * kN + 1 + s) * k3C + h * kD + j;
  Qb[idx] = f2bf(qkv[src] * kScale);
  Kb[idx] = f2bf(qkv[src + kC]);
}

// ---------- pack V transposed: Vt[bh*8+f][64][224] bf16 ----------
__global__ void pack_vt_k(const float* __restrict__ qkv, ushort* __restrict__ Vt) {
  const int idx = blockIdx.x * 256 + threadIdx.x;
  if (idx >= kBH * kF * kD * kPpad) return;
  const int n = idx % kPpad;
  const int j = (idx / kPpad) & 63;
  const int f = (idx / (kPpad * kD)) & 7;
  const int bh = idx / (kPpad * kD * kF);
  const int b = bh / kH, h = bh % kH;
  float v = 0.f;
  if (n < kP)
    v = qkv[(size_t)(b * kN + 1 + f * kP + n) * k3C + 2 * kC + h * kD + j];
  Vt[idx] = f2bf(v);
}

// ---------- spatial attention, swapped-QK^T, LDS-free ----------
__global__ __launch_bounds__(256) void sp_attn_mfma(
    const ushort* __restrict__ Qb, const ushort* __restrict__ Kb,
    const ushort* __restrict__ Vt, ushort* __restrict__ x4b) {
  const int w = threadIdx.x >> 6;
  const int lane = threadIdx.x & 63;
  const int fbh = blockIdx.x;
  const int f = fbh / 24, bh = fbh % 24;
  const int tile = blockIdx.y * 4 + w;  // 0..48 valid
  if (tile >= 49) return;
  const int q0 = tile * 32;
  const int lr = lane & 15;
  const int lg = lane >> 4;

  const ushort* qrow = Qb + ((size_t)bh * kS + q0 + lr) * kD + lg * 8;
  const bf16x8 a00 = *(const bf16x8*)qrow;
  const bf16x8 a01 = *(const bf16x8*)(qrow + 32);
  const bf16x8 a10 = *(const bf16x8*)(qrow + 16 * kD);
  const bf16x8 a11 = *(const bf16x8*)(qrow + 16 * kD + 32);

  f32x4 s0[13], s1[13];
  const ushort* kbase = Kb + ((size_t)bh * kS + f * kP + lr) * kD + lg * 8;
#pragma unroll
  for (int nt = 0; nt < 13; ++nt) {
    const ushort* kr = kbase + (size_t)nt * 16 * kD;
    bf16x8 b0 = *(const bf16x8*)kr;
    bf16x8 b1 = *(const bf16x8*)(kr + 32);
    f32x4 acc0 = {0.f, 0.f, 0.f, 0.f}, acc1 = {0.f, 0.f, 0.f, 0.f};
    acc0 = __builtin_amdgcn_mfma_f32_16x16x32_bf16(b0, a00, acc0, 0, 0, 0);
    acc0 = __builtin_amdgcn_mfma_f32_16x16x32_bf16(b1, a01, acc0, 0, 0, 0);
    acc1 = __builtin_amdgcn_mfma_f32_16x16x32_bf16(b0, a10, acc1, 0, 0, 0);
    acc1 = __builtin_amdgcn_mfma_f32_16x16x32_bf16(b1, a11, acc1, 0, 0, 0);
    s0[nt] = acc0;
    s1[nt] = acc1;
  }
  if (lg >= 1) {
#pragma unroll
    for (int r = 0; r < 4; ++r) { s0[12][r] = -1e30f; s1[12][r] = -1e30f; }
  }

  float m0 = -1e30f, m1 = -1e30f;
#pragma unroll
  for (int nt = 0; nt < 13; ++nt)
#pragma unroll
    for (int r = 0; r < 4; ++r) {
      m0 = fmaxf(m0, s0[nt][r]);
      m1 = fmaxf(m1, s1[nt][r]);
    }
  m0 = fmaxf(m0, __shfl_xor(m0, 16));
  m0 = fmaxf(m0, __shfl_xor(m0, 32));
  m1 = fmaxf(m1, __shfl_xor(m1, 16));
  m1 = fmaxf(m1, __shfl_xor(m1, 32));

  float sum0 = 0.f, sum1 = 0.f;
  u32x4 breg0[7], breg1[7];
#pragma unroll
  for (int blk = 0; blk < 7; ++blk) {
    unsigned pk0[2][2], pk1[2][2];
#pragma unroll
    for (int t = 0; t < 2; ++t) {
      const int nt = blk * 2 + t;
      if (nt < 13) {
        float e0 = __expf(s0[nt][0] - m0), e1 = __expf(s0[nt][1] - m0);
        float e2 = __expf(s0[nt][2] - m0), e3 = __expf(s0[nt][3] - m0);
        sum0 += (e0 + e1) + (e2 + e3);
        pk0[t][0] = ((unsigned)f2bf(e1) << 16) | f2bf(e0);
        pk0[t][1] = ((unsigned)f2bf(e3) << 16) | f2bf(e2);
        float g0 = __expf(s1[nt][0] - m1), g1 = __expf(s1[nt][1] - m1);
        float g2 = __expf(s1[nt][2] - m1), g3 = __expf(s1[nt][3] - m1);
        sum1 += (g0 + g1) + (g2 + g3);
        pk1[t][0] = ((unsigned)f2bf(g1) << 16) | f2bf(g0);
        pk1[t][1] = ((unsigned)f2bf(g3) << 16) | f2bf(g2);
      } else {
        pk0[t][0] = 0; pk0[t][1] = 0;
        pk1[t][0] = 0; pk1[t][1] = 0;
      }
    }
#pragma unroll
    for (int j2 = 0; j2 < 4; ++j2) {
      const int srcLane = ((lg & 1) * 2 + (j2 >> 1)) * 16 + lr;
      unsigned t0 = (unsigned)__shfl((int)pk0[0][j2 & 1], srcLane);
      unsigned t1 = (unsigned)__shfl((int)pk0[1][j2 & 1], srcLane);
      breg0[blk][j2] = (lg < 2) ? t0 : t1;
      unsigned u0 = (unsigned)__shfl((int)pk1[0][j2 & 1], srcLane);
      unsigned u1 = (unsigned)__shfl((int)pk1[1][j2 & 1], srcLane);
      breg1[blk][j2] = (lg < 2) ? u0 : u1;
    }
  }
  sum0 += __shfl_xor(sum0, 16);
  sum0 += __shfl_xor(sum0, 32);
  sum1 += __shfl_xor(sum1, 16);
  sum1 += __shfl_xor(sum1, 32);
  const float inv0 = 1.f / sum0, inv1 = 1.f / sum1;

  const ushort* vbase = Vt + ((size_t)(bh * kF + f) * kD + lr) * kPpad + lg * 8;
  f32x4 o0[4] = {}, o1[4] = {};
#pragma unroll
  for (int nt2 = 0; nt2 < 4; ++nt2) {
    const ushort* vb = vbase + (size_t)nt2 * 16 * kPpad;
#pragma unroll
    for (int blk = 0; blk < 7; ++blk) {
      bf16x8 av = *(const bf16x8*)(vb + blk * 32);
      bf16x8 pb0 = __builtin_bit_cast(bf16x8, breg0[blk]);
      bf16x8 pb1 = __builtin_bit_cast(bf16x8, breg1[blk]);
      o0[nt2] = __builtin_amdgcn_mfma_f32_16x16x32_bf16(av, pb0, o0[nt2], 0, 0, 0);
      o1[nt2] = __builtin_amdgcn_mfma_f32_16x16x32_bf16(av, pb1, o1[nt2], 0, 0, 0);
    }
  }

  const int b = bh / kH, h = bh % kH;
  const size_t base0 =
      ((size_t)(b * kS + q0 + lr) * kF + f) * kC + h * kD + lg * 4;
#pragma unroll
  for (int nt2 = 0; nt2 < 4; ++nt2) {
    ushort4 v0, v1;
    v0.x = f2bf(o0[nt2][0] * inv0);
    v0.y = f2bf(o0[nt2][1] * inv0);
    v0.z = f2bf(o0[nt2][2] * inv0);
    v0.w = f2bf(o0[nt2][3] * inv0);
    *(ushort4*)(x4b + base0 + nt2 * 16) = v0;
    v1.x = f2bf(o1[nt2][0] * inv1);
    v1.y = f2bf(o1[nt2][1] * inv1);
    v1.z = f2bf(o1[nt2][2] * inv1);
    v1.w = f2bf(o1[nt2][3] * inv1);
    *(ushort4*)(x4b + base0 + (size_t)16 * kF * kC + nt2 * 16) = v1;
  }
}

// ---------- cls attention, 4-phase parallel ----------
__global__ __launch_bounds__(256) void cls_logits_k(const float* __restrict__ qkv,
                                                    float* __restrict__ logits) {
  const int chunk = blockIdx.x, bh = blockIdx.y;
  const int b = bh / kH, h = bh % kH;
  const int g = threadIdx.x & 15, row = threadIdx.x >> 4;
  const size_t base = (size_t)b * kN * k3C;
  float4 q4 = *(const float4*)(qkv + base + h * kD + g * 4);
  q4.x *= kScale; q4.y *= kScale; q4.z *= kScale; q4.w *= kScale;
#pragma unroll
  for (int i = 0; i < 16; ++i) {
    const int n = chunk * 256 + i * 16 + row;
    if (n < kN) {
      const float4 kv =
          *(const float4*)(qkv + base + (size_t)n * k3C + kC + h * kD + g * 4);
      float p = q4.x * kv.x + q4.y * kv.y + q4.z * kv.z + q4.w * kv.w;
#pragma unroll
      for (int o = 8; o; o >>= 1) p += __shfl_xor(p, o, 16);
      if (g == 0) logits[bh * kLpad + n] = p;
    }
  }
}

__global__ __launch_bounds__(256) void cls_softmax_k(const float* __restrict__ logits,
                                                     float* __restrict__ pbuf) {
  __shared__ float red[8];
  const int bh = blockIdx.x, tid = threadIdx.x;
  float m = -1e30f;
  for (int n = tid; n < kN; n += 256) m = fmaxf(m, logits[bh * kLpad + n]);
#pragma unroll
  for (int o = 32; o; o >>= 1) m = fmaxf(m, __shfl_xor(m, o));
  if ((tid & 63) == 0) red[tid >> 6] = m;
  __syncthreads();
  m = fmaxf(fmaxf(red[0], red[1]), fmaxf(red[2], red[3]));
  float sum = 0.f;
  for (int n = tid; n < kN; n += 256) sum += __expf(logits[bh * kLpad + n] - m);
#pragma unroll
  for (int o = 32; o; o >>= 1) sum += __shfl_xor(sum, o);
  if ((tid & 63) == 0) red[4 + (tid >> 6)] = sum;
  __syncthreads();
  const float inv = 1.f / (red[4] + red[5] + red[6] + red[7]);
  for (int n = tid; n < kN; n += 256)
    pbuf[bh * kLpad + n] = __expf(logits[bh * kLpad + n] - m) * inv;
}

__global__ __launch_bounds__(256) void cls_pv_k(const float* __restrict__ qkv,
                                                const float* __restrict__ pbuf,
                                                float* __restrict__ partial) {
  __shared__ float pb[256];
  const int chunk = blockIdx.x, bh = blockIdx.y;
  const int b = bh / kH, h = bh % kH;
  const int j = threadIdx.x & 63, part = threadIdx.x >> 6;
  const size_t base = (size_t)b * kN * k3C + 2 * kC + h * kD + j;
  float acc = 0.f;
#pragma unroll 4
  for (int i = 0; i < 64; ++i) {
    const int n = chunk * 256 + i * 4 + part;
    if (n < kN) acc = fmaf(pbuf[bh * kLpad + n], qkv[base + (size_t)n * k3C], acc);
  }
  pb[threadIdx.x] = acc;
  __syncthreads();
  if (part == 0)
    partial[((size_t)bh * 7 + chunk) * kD + j] =
        pb[j] + pb[64 + j] + pb[128 + j] + pb[192 + j];
}

__global__ void cls_red_k(const float* __restrict__ partial,
                          ushort* __restrict__ xin_b) {
  const int bh = blockIdx.x, j = threadIdx.x;
  const int b = bh / kH, h = bh % kH;
  float s = 0.f;
#pragma unroll
  for (int c = 0; c < 7; ++c) s += partial[((size_t)bh * 7 + c) * kD + j];
  xin_b[(size_t)(b * kN) * kC + h * kD + j] = f2bf(s);
}

// ---------- xd gather (bf16 -> bf16) ----------
__global__ void xd_gather_k(const ushort* __restrict__ x4b,
                            ushort* __restrict__ xd_b) {
  const int idx = blockIdx.x * 256 + threadIdx.x;
  const int total = kB * kS * (kC / 8);
  if (idx >= total) return;
  const int row = idx / (kC / 8);
  const int cg = idx - row * (kC / 8);
  const int b = row / kS, s = row - b * kS;
  const int fq = s / kP;
  ((ulonglong2*)xd_b)[(size_t)row * (kC / 8) + cg] =
      ((const ulonglong2*)x4b)[((size_t)(b * kS + s) * kF + fq) * (kC / 8) + cg];
}

// ---------- fused temporal attention: one block per (b,s) ----------
// logit[f,h] = x4[bs,f,:] . w2[bs,h,:]; softmax over f; outputs xin + attn2.
__global__ __launch_bounds__(256) void attn2_fused(
    const ushort* __restrict__ x4b, const ushort* __restrict__ w2b,
    ushort* __restrict__ xin_b, float* __restrict__ attn2out) {
  __shared__ __align__(16) ushort x4s[kF * kC];   // 12 KB
  __shared__ __align__(16) ushort w2s[kH * kC];   // 18 KB
  const int bs = blockIdx.x;
  const int b = bs / kS, s = bs - b * kS;
  const int tid = threadIdx.x;
  {
    const ulonglong2* src = (const ulonglong2*)(x4b + (size_t)bs * kF * kC);
    ulonglong2* dst = (ulonglong2*)x4s;
    for (int i = tid; i < kF * kC / 8; i += 256) dst[i] = src[i];
    const ulonglong2* srcw = (const ulonglong2*)(w2b + (size_t)bs * kH * kC);
    ulonglong2* dstw = (ulonglong2*)w2s;
    for (int i = tid; i < kH * kC / 8; i += 256) dstw[i] = srcw[i];
  }
  __syncthreads();
  const int w = tid >> 6, lane = tid & 63;
#pragma unroll
  for (int hh = 0; hh < 3; ++hh) {
    const int h = w * 3 + hh;
    float part[kF] = {};
#pragma unroll
    for (int i = 0; i < 3; ++i) {
      const int c = lane * 4 + i * 256;
      ushort4 wv = *(const ushort4*)&w2s[h * kC + c];
      const float w0 = bf2f(wv.x), w1 = bf2f(wv.y);
      const float w2v = bf2f(wv.z), w3 = bf2f(wv.w);
#pragma unroll
      for (int f = 0; f < kF; ++f) {
        ushort4 xv = *(const ushort4*)&x4s[f * kC + c];
        part[f] += bf2f(xv.x) * w0 + bf2f(xv.y) * w1 + bf2f(xv.z) * w2v +
                   bf2f(xv.w) * w3;
      }
    }
    float l[kF];
#pragma unroll
    for (int f = 0; f < kF; ++f) {
      float p = part[f];
#pragma unroll
      for (int o = 32; o; o >>= 1) p += __shfl_xor(p, o);
      l[f] = p;
    }
    float m = l[0];
#pragma unroll
    for (int f = 1; f < kF; ++f) m = fmaxf(m, l[f]);
    float sum = 0.f;
#pragma unroll
    for (int f = 0; f < kF; ++f) {
      l[f] = __expf(l[f] - m);
      sum += l[f];
    }
    const float inv = 1.f / sum;
    // attn2 probs: lane f<8 writes l[f]*inv (compile-time-indexed select chain)
    float pv = 0.f;
#pragma unroll
    for (int f = 0; f < kF; ++f) pv = (lane == f) ? l[f] : pv;
    if (lane < kF)
      attn2out[((size_t)(b * kH + h) * kS + s) * kF + lane] = pv * inv;
    // weighted sum over f: lane = d within head
    float o = 0.f;
#pragma unroll
    for (int f = 0; f < kF; ++f)
      o = fmaf(l[f] * inv, bf2f(x4s[f * kC + h * kD + lane]), o);
    xin_b[(size_t)(b * kN + 1 + s) * kC + h * kD + lane] = f2bf(o);
  }
}

extern "C" void kernel_launch(void* const* d_in, const int* in_sizes, int n_in,
                              void* d_out, int out_size, void* d_ws,
                              size_t ws_size, hipStream_t stream) {
  const float* x = (const float*)d_in[0];
  const float* Wqkv = (const float*)d_in[1];
  const float* Wq = (const float*)d_in[2];
  const float* Wkv = (const float*)d_in[3];
  const float* Wproj = (const float*)d_in[4];
  const float* bproj = (const float*)d_in[5];

  char* p = (char*)d_ws;
  float* qkv = (float*)p;            p += (size_t)3138 * 2304 * 4;
  ushort* w2b = (ushort*)p;          p += (size_t)kBS * kH * kC * 2;   // 57.8MB
  ushort* q2b = (ushort*)p;          p += (size_t)kBS * kC * 2;
  ushort* x4b = (ushort*)p;          p += (size_t)25088 * 768 * 2;
  ushort* xin_b = (ushort*)p;        p += (size_t)3138 * 768 * 2;
  ushort* xd_b = (ushort*)p;         p += (size_t)kBS * 768 * 2;
  ushort* xb = (ushort*)p;           p += (size_t)3138 * 768 * 2;
  ushort* Wqkv_t = (ushort*)p;       p += (size_t)2304 * 768 * 2;
  ushort* Wq_t = (ushort*)p;         p += (size_t)768 * 768 * 2;
  ushort* Wkvb = (ushort*)p;         p += (size_t)768 * 768 * 2;
  ushort* Wproj_t = (ushort*)p;      p += (size_t)768 * 768 * 2;
  ushort* Qb = (ushort*)p;           p += (size_t)kBH * kS * kD * 2;
  ushort* Kb = (ushort*)p;           p += ((size_t)kBH * kS + 16) * kD * 2;
  ushort* Vt = (ushort*)p;           p += (size_t)kBH * kF * kD * kPpad * 2;
  float* clsL = (float*)p;           p += (size_t)kBH * kLpad * 4;
  float* clsP = (float*)p;           p += (size_t)kBH * kLpad * 4;
  float* clsPart = (float*)p;

  float* out = (float*)d_out;
  float* attn2 = out + (size_t)kB * kN * kC;

  // 0. packs (kScale folded exactly into Wq_t: 0.125 is a power of 2)
  pack_x_k<<<(3138 * 768 / 4 + 255) / 256, 256, 0, stream>>>(x, xb, 3138 * 768 / 4);
  pack_wt_k<<<dim3(72, 24), 256, 0, stream>>>(Wqkv, Wqkv_t, 2304, 1.f);
  pack_wt_k<<<dim3(24, 24), 256, 0, stream>>>(Wq, Wq_t, 768, kScale);
  pack_wkv_k<<<(768 * 192 + 255) / 256, 256, 0, stream>>>(Wkv, Wkvb);
  pack_wt_k<<<dim3(24, 24), 256, 0, stream>>>(Wproj, Wproj_t, 768, 1.f);
  // 1. qkv = x @ Wqkv (fp32 out, feeds cls + packs)
  gemm_bf16<float><<<18 * 25, 256, 0, stream>>>(xb, Wqkv_t, nullptr, qkv, 3138,
                                                2304, 768, 18);
  // 2. pack attention operands
  pack_qk_k<<<(kBH * kS * kD + 255) / 256, 256, 0, stream>>>(qkv, Qb, Kb);
  pack_vt_k<<<(kBH * kF * kD * kPpad + 255) / 256, 256, 0, stream>>>(qkv, Vt);
  // 3. cls attention (4-phase)
  cls_logits_k<<<dim3(7, 24), 256, 0, stream>>>(qkv, clsL);
  cls_softmax_k<<<24, 256, 0, stream>>>(clsL, clsP);
  cls_pv_k<<<dim3(7, 24), 256, 0, stream>>>(qkv, clsP, clsPart);
  cls_red_k<<<24, 64, 0, stream>>>(clsPart, xin_b);
  // 4. spatial attention -> x4b (LDS-free, XCD-local via grid.x = f*24+bh)
  sp_attn_mfma<<<dim3(192, 13), 256, 0, stream>>>(Qb, Kb, Vt, x4b);
  // 5. xd gather
  xd_gather_k<<<(kB * kS * (kC / 8) + 255) / 256, 256, 0, stream>>>(x4b, xd_b);
  // 6. q2 = xd @ (Wq * scale)  (bf16 out, pre-scaled)
  gemm_bf16<ushort><<<6 * 25, 256, 0, stream>>>(xd_b, Wq_t, nullptr, q2b, kBS,
                                                768, 768, 6);
  // 7. w2[bs,h,:] = Wkv_h^T @ q2[bs,h,:]  (replaces the 25088x768x768 k2 GEMM)
  w2_gemm<<<1800, 256, 0, stream>>>(q2b, Wkvb, w2b);
  // 8. fused temporal attention (logits via associativity, x4 read once)
  attn2_fused<<<kBS, 256, 0, stream>>>(x4b, w2b, xin_b, attn2);
  // 9. out = xin @ Wproj + bproj (fp32 out)
  gemm_bf16<float><<<6 * 25, 256, 0, stream>>>(xin_b, Wproj_t, bproj, out, 3138,
                                               768, 768, 6);
}

// Round 9
// 263.194 us; speedup vs baseline: 6.0344x; 1.0135x over previous
//
#include <hip/hip_runtime.h>

namespace {
constexpr int kB = 2;
constexpr int kH = 12;
constexpr int kD = 64;
constexpr int kC = 768;
constexpr int kF = 8;
constexpr int kP = 196;
constexpr int kS = kF * kP;      // 1568
constexpr int kN = 1 + kS;       // 1569
constexpr int k3C = 3 * kC;      // 2304
constexpr float kScale = 0.125f; // d^-0.5 (exact power of 2)
constexpr int kBH = kB * kH;     // 24
constexpr int kPpad = 224;       // keys padded for PV K-dim (7x32)
constexpr int kLpad = 1600;      // cls logits row stride
constexpr int kBS = kB * kS;     // 3136
}

typedef __attribute__((ext_vector_type(8))) short bf16x8;
typedef __attribute__((ext_vector_type(8))) unsigned short u16x8;
typedef __attribute__((ext_vector_type(4))) float f32x4;
typedef __attribute__((ext_vector_type(4))) unsigned int u32x4;

__device__ inline ushort f2bf(float x) {
  union { float f; unsigned u; } v{x};
  unsigned r = v.u + 0x7fff + ((v.u >> 16) & 1);
  return (ushort)(r >> 16);
}
__device__ inline float bf2f(ushort u) {
  union { unsigned u; float f; } v{(unsigned)u << 16};
  return v.f;
}

__device__ __forceinline__ void gload_lds16(const void* g, void* l) {
  __builtin_amdgcn_global_load_lds(
      (const __attribute__((address_space(1))) unsigned int*)g,
      (__attribute__((address_space(3))) unsigned int*)l, 16, 0, 0);
}

__device__ inline void storeC(float v, float* p) { *p = v; }
__device__ inline void storeC(float v, ushort* p) { *p = f2bf(v); }

// ---------- bf16 MFMA GEMM: C[M,N] = A[M,K]bf16 @ Bt[N,K]bf16^T (+bias) ----
template <typename OutT>
__global__ __launch_bounds__(256) void gemm_bf16(
    const ushort* __restrict__ A, const ushort* __restrict__ Bt,
    const float* __restrict__ bias, OutT* __restrict__ C,
    int M, int N, int K, int nbx) {
  const int nwg = gridDim.x;
  const int q = nwg >> 3, rr = nwg & 7;
  const int xcd = blockIdx.x & 7, loc = blockIdx.x >> 3;
  const int vid = ((xcd < rr) ? xcd * (q + 1) : rr * (q + 1) + (xcd - rr) * q) + loc;
  const int m0 = (vid / nbx) * 128, n0 = (vid % nbx) * 128;

  __shared__ __align__(16) ushort As[128 * 32];
  __shared__ __align__(16) ushort Bs[128 * 32];
  const int tid = threadIdx.x;
  const int r0 = tid >> 2, c0 = tid & 3;
  const int r1 = r0 + 64;
  const int sc0 = (c0 ^ ((r0 >> 1) & 3)) * 8;
  const int sc1 = (c0 ^ ((r1 >> 1) & 3)) * 8;
  const int ar0 = min(m0 + r0, M - 1), ar1 = min(m0 + r1, M - 1);
  const ushort* ga0 = A + (size_t)ar0 * K + sc0;
  const ushort* ga1 = A + (size_t)ar1 * K + sc1;
  const ushort* gb0 = Bt + (size_t)(n0 + r0) * K + sc0;
  const ushort* gb1 = Bt + (size_t)(n0 + r1) * K + sc1;
  const int w = tid >> 6;
  char* lA0 = (char*)As + w * 1024;
  char* lA1 = (char*)As + 4096 + w * 1024;
  char* lB0 = (char*)Bs + w * 1024;
  char* lB1 = (char*)Bs + 4096 + w * 1024;
  const int lane = tid & 63;
  const int lr = lane & 15, lg = lane >> 4;
  const int wr = w >> 1, wc = w & 1;
  f32x4 acc[4][4] = {};
  for (int kt = 0; kt < K; kt += 32) {
    gload_lds16(ga0 + kt, lA0);
    gload_lds16(ga1 + kt, lA1);
    gload_lds16(gb0 + kt, lB0);
    gload_lds16(gb1 + kt, lB1);
    __syncthreads();
    bf16x8 af[4], bfr[4];
#pragma unroll
    for (int m = 0; m < 4; ++m) {
      int row = wr * 64 + m * 16 + lr;
      int ch = lg ^ ((row >> 1) & 3);
      af[m] = *(const bf16x8*)(As + row * 32 + ch * 8);
    }
#pragma unroll
    for (int n = 0; n < 4; ++n) {
      int row = wc * 64 + n * 16 + lr;
      int ch = lg ^ ((row >> 1) & 3);
      bfr[n] = *(const bf16x8*)(Bs + row * 32 + ch * 8);
    }
#pragma unroll
    for (int m = 0; m < 4; ++m)
#pragma unroll
      for (int n = 0; n < 4; ++n)
        acc[m][n] =
            __builtin_amdgcn_mfma_f32_16x16x32_bf16(af[m], bfr[n], acc[m][n], 0, 0, 0);
    __syncthreads();
  }
#pragma unroll
  for (int m = 0; m < 4; ++m) {
#pragma unroll
    for (int r = 0; r < 4; ++r) {
      const int mg = m0 + wr * 64 + m * 16 + lg * 4 + r;
      if (mg < M) {
        OutT* crow = C + (size_t)mg * N + n0 + wc * 64 + lr;
#pragma unroll
        for (int n = 0; n < 4; ++n) {
          float v = acc[m][n][r];
          if (bias) v += bias[n0 + wc * 64 + n * 16 + lr];
          storeC(v, crow + n * 16);
        }
      }
    }
  }
}

// ---------- w2[bs][h][c] = sum_d q2b[bs][h*64+d] * Wkvb[c][h*64+d] ----------
__global__ __launch_bounds__(256) void w2_gemm(
    const ushort* __restrict__ q2b, const ushort* __restrict__ Wkvb,
    ushort* __restrict__ w2b) {
  const int nwg = gridDim.x;
  const int q = nwg >> 3, rr = nwg & 7;
  const int xcd = blockIdx.x & 7, loc = blockIdx.x >> 3;
  const int vid = ((xcd < rr) ? xcd * (q + 1) : rr * (q + 1) + (xcd - rr) * q) + loc;
  const int h = vid / 150;
  const int rem = vid - h * 150;
  const int m0 = (rem / 6) * 128, n0 = (rem % 6) * 128;

  __shared__ __align__(16) ushort As[128 * 32];
  __shared__ __align__(16) ushort Bs[128 * 32];
  const int tid = threadIdx.x;
  const int r0 = tid >> 2, c0 = tid & 3;
  const int r1 = r0 + 64;
  const int sc0 = (c0 ^ ((r0 >> 1) & 3)) * 8;
  const int sc1 = (c0 ^ ((r1 >> 1) & 3)) * 8;
  const int ar0 = min(m0 + r0, kBS - 1), ar1 = min(m0 + r1, kBS - 1);
  const ushort* ga0 = q2b + (size_t)ar0 * kC + h * 64 + sc0;
  const ushort* ga1 = q2b + (size_t)ar1 * kC + h * 64 + sc1;
  const ushort* gb0 = Wkvb + (size_t)(n0 + r0) * kC + h * 64 + sc0;
  const ushort* gb1 = Wkvb + (size_t)(n0 + r1) * kC + h * 64 + sc1;
  const int w = tid >> 6;
  char* lA0 = (char*)As + w * 1024;
  char* lA1 = (char*)As + 4096 + w * 1024;
  char* lB0 = (char*)Bs + w * 1024;
  char* lB1 = (char*)Bs + 4096 + w * 1024;
  const int lane = tid & 63;
  const int lr = lane & 15, lg = lane >> 4;
  const int wr = w >> 1, wc = w & 1;
  f32x4 acc[4][4] = {};
#pragma unroll
  for (int kt = 0; kt < 64; kt += 32) {
    gload_lds16(ga0 + kt, lA0);
    gload_lds16(ga1 + kt, lA1);
    gload_lds16(gb0 + kt, lB0);
    gload_lds16(gb1 + kt, lB1);
    __syncthreads();
    bf16x8 af[4], bfr[4];
#pragma unroll
    for (int m = 0; m < 4; ++m) {
      int row = wr * 64 + m * 16 + lr;
      int ch = lg ^ ((row >> 1) & 3);
      af[m] = *(const bf16x8*)(As + row * 32 + ch * 8);
    }
#pragma unroll
    for (int n = 0; n < 4; ++n) {
      int row = wc * 64 + n * 16 + lr;
      int ch = lg ^ ((row >> 1) & 3);
      bfr[n] = *(const bf16x8*)(Bs + row * 32 + ch * 8);
    }
#pragma unroll
    for (int m = 0; m < 4; ++m)
#pragma unroll
      for (int n = 0; n < 4; ++n)
        acc[m][n] =
            __builtin_amdgcn_mfma_f32_16x16x32_bf16(af[m], bfr[n], acc[m][n], 0, 0, 0);
    __syncthreads();
  }
#pragma unroll
  for (int m = 0; m < 4; ++m) {
#pragma unroll
    for (int r = 0; r < 4; ++r) {
      const int mg = m0 + wr * 64 + m * 16 + lg * 4 + r;
      if (mg < kBS) {
        ushort* crow = w2b + (size_t)mg * (kH * kC) + h * kC + n0 + wc * 64 + lr;
#pragma unroll
        for (int n = 0; n < 4; ++n) crow[n * 16] = f2bf(acc[m][n][r]);
      }
    }
  }
}

// ---------- pack x -> bf16 ----------
__global__ void pack_x_k(const float* __restrict__ X, ushort* __restrict__ Xb,
                         int n4) {
  const int i = blockIdx.x * 256 + threadIdx.x;
  if (i >= n4) return;
  float4 v = ((const float4*)X)[i];
  ushort4 o = {f2bf(v.x), f2bf(v.y), f2bf(v.z), f2bf(v.w)};
  ((ushort4*)Xb)[i] = o;
}

// ---------- pack W[768][ldw] cols[0,Ncols) -> Wt[Ncols][768] bf16 (xscale) ----
__global__ __launch_bounds__(256) void pack_wt_k(const float* __restrict__ W,
                                                 ushort* __restrict__ Wt,
                                                 int ldw, float scale) {
  __shared__ float t[32][33];
  const int nb = blockIdx.x * 32;
  const int kb = blockIdx.y * 32;
  const int tx = threadIdx.x & 31, ty = threadIdx.x >> 5;
#pragma unroll
  for (int i = 0; i < 32; i += 8)
    t[ty + i][tx] = W[(size_t)(kb + ty + i) * ldw + nb + tx];
  __syncthreads();
#pragma unroll
  for (int i = 0; i < 32; i += 8)
    Wt[(size_t)(nb + ty + i) * 768 + kb + tx] = f2bf(t[tx][ty + i] * scale);
}

// ---------- pack Wkv[:, :768] -> Wkvb[768][768] bf16 (no transpose) ----------
__global__ void pack_wkv_k(const float* __restrict__ Wkv,
                           ushort* __restrict__ Wkvb) {
  const int i = blockIdx.x * 256 + threadIdx.x;  // over 768*192 float4s
  if (i >= 768 * 192) return;
  const int c = i / 192, j4 = i - c * 192;
  float4 v = *(const float4*)(Wkv + (size_t)c * 1536 + j4 * 4);
  ushort4 o = {f2bf(v.x), f2bf(v.y), f2bf(v.z), f2bf(v.w)};
  *(ushort4*)(Wkvb + (size_t)c * 768 + j4 * 4) = o;
}

// ---------- pack q,k (scaled q, exact 2^-3) from bf16 qkv; 16B/lane ----------
__global__ void pack_qk_k(const ushort* __restrict__ qkvb,
                          ushort* __restrict__ Qb, ushort* __restrict__ Kb) {
  const int idx = blockIdx.x * 256 + threadIdx.x;  // over kBH*kS*8 groups
  if (idx >= kBH * kS * 8) return;
  const int j8 = idx & 7;
  const int s = (idx >> 3) % kS;
  const int bh = idx / (kS * 8);
  const int b = bh / kH, h = bh % kH;
  const size_t src = (size_t)(b * kN + 1 + s) * k3C + h * kD + j8 * 8;
  u16x8 qv = *(const u16x8*)(qkvb + src);
  u16x8 qo;
#pragma unroll
  for (int j = 0; j < 8; ++j) qo[j] = f2bf(bf2f(qv[j]) * kScale);  // exact
  const size_t dst = ((size_t)bh * kS + s) * kD + j8 * 8;
  *(u16x8*)(Qb + dst) = qo;
  *(u16x8*)(Kb + dst) = *(const u16x8*)(qkvb + src + kC);
}

// ---------- pack V transposed: Vt[bh*8+f][64][224] bf16 ----------
__global__ void pack_vt_k(const ushort* __restrict__ qkvb,
                          ushort* __restrict__ Vt) {
  const int idx = blockIdx.x * 256 + threadIdx.x;
  if (idx >= kBH * kF * kD * kPpad) return;
  const int n = idx % kPpad;
  const int j = (idx / kPpad) & 63;
  const int f = (idx / (kPpad * kD)) & 7;
  const int bh = idx / (kPpad * kD * kF);
  const int b = bh / kH, h = bh % kH;
  ushort v = 0;
  if (n < kP)
    v = qkvb[(size_t)(b * kN + 1 + f * kP + n) * k3C + 2 * kC + h * kD + j];
  Vt[idx] = v;
}

// ---------- spatial attention, swapped-QK^T, LDS-free (round-7 proven) ----------
__global__ __launch_bounds__(256) void sp_attn_mfma(
    const ushort* __restrict__ Qb, const ushort* __restrict__ Kb,
    const ushort* __restrict__ Vt, ushort* __restrict__ x4b) {
  const int w = threadIdx.x >> 6;
  const int lane = threadIdx.x & 63;
  const int fbh = blockIdx.x;
  const int f = fbh / 24, bh = fbh % 24;
  const int tile = blockIdx.y * 4 + w;  // 0..48 valid
  if (tile >= 49) return;
  const int q0 = tile * 32;
  const int lr = lane & 15;
  const int lg = lane >> 4;

  const ushort* qrow = Qb + ((size_t)bh * kS + q0 + lr) * kD + lg * 8;
  const bf16x8 a00 = *(const bf16x8*)qrow;
  const bf16x8 a01 = *(const bf16x8*)(qrow + 32);
  const bf16x8 a10 = *(const bf16x8*)(qrow + 16 * kD);
  const bf16x8 a11 = *(const bf16x8*)(qrow + 16 * kD + 32);

  f32x4 s0[13], s1[13];
  const ushort* kbase = Kb + ((size_t)bh * kS + f * kP + lr) * kD + lg * 8;
#pragma unroll
  for (int nt = 0; nt < 13; ++nt) {
    const ushort* kr = kbase + (size_t)nt * 16 * kD;
    bf16x8 b0 = *(const bf16x8*)kr;
    bf16x8 b1 = *(const bf16x8*)(kr + 32);
    f32x4 acc0 = {0.f, 0.f, 0.f, 0.f}, acc1 = {0.f, 0.f, 0.f, 0.f};
    acc0 = __builtin_amdgcn_mfma_f32_16x16x32_bf16(b0, a00, acc0, 0, 0, 0);
    acc0 = __builtin_amdgcn_mfma_f32_16x16x32_bf16(b1, a01, acc0, 0, 0, 0);
    acc1 = __builtin_amdgcn_mfma_f32_16x16x32_bf16(b0, a10, acc1, 0, 0, 0);
    acc1 = __builtin_amdgcn_mfma_f32_16x16x32_bf16(b1, a11, acc1, 0, 0, 0);
    s0[nt] = acc0;
    s1[nt] = acc1;
  }
  if (lg >= 1) {
#pragma unroll
    for (int r = 0; r < 4; ++r) { s0[12][r] = -1e30f; s1[12][r] = -1e30f; }
  }

  float m0 = -1e30f, m1 = -1e30f;
#pragma unroll
  for (int nt = 0; nt < 13; ++nt)
#pragma unroll
    for (int r = 0; r < 4; ++r) {
      m0 = fmaxf(m0, s0[nt][r]);
      m1 = fmaxf(m1, s1[nt][r]);
    }
  m0 = fmaxf(m0, __shfl_xor(m0, 16));
  m0 = fmaxf(m0, __shfl_xor(m0, 32));
  m1 = fmaxf(m1, __shfl_xor(m1, 16));
  m1 = fmaxf(m1, __shfl_xor(m1, 32));

  float sum0 = 0.f, sum1 = 0.f;
  u32x4 breg0[7], breg1[7];
#pragma unroll
  for (int blk = 0; blk < 7; ++blk) {
    unsigned pk0[2][2], pk1[2][2];
#pragma unroll
    for (int t = 0; t < 2; ++t) {
      const int nt = blk * 2 + t;
      if (nt < 13) {
        float e0 = __expf(s0[nt][0] - m0), e1 = __expf(s0[nt][1] - m0);
        float e2 = __expf(s0[nt][2] - m0), e3 = __expf(s0[nt][3] - m0);
        sum0 += (e0 + e1) + (e2 + e3);
        pk0[t][0] = ((unsigned)f2bf(e1) << 16) | f2bf(e0);
        pk0[t][1] = ((unsigned)f2bf(e3) << 16) | f2bf(e2);
        float g0 = __expf(s1[nt][0] - m1), g1 = __expf(s1[nt][1] - m1);
        float g2 = __expf(s1[nt][2] - m1), g3 = __expf(s1[nt][3] - m1);
        sum1 += (g0 + g1) + (g2 + g3);
        pk1[t][0] = ((unsigned)f2bf(g1) << 16) | f2bf(g0);
        pk1[t][1] = ((unsigned)f2bf(g3) << 16) | f2bf(g2);
      } else {
        pk0[t][0] = 0; pk0[t][1] = 0;
        pk1[t][0] = 0; pk1[t][1] = 0;
      }
    }
#pragma unroll
    for (int j2 = 0; j2 < 4; ++j2) {
      const int srcLane = ((lg & 1) * 2 + (j2 >> 1)) * 16 + lr;
      unsigned t0 = (unsigned)__shfl((int)pk0[0][j2 & 1], srcLane);
      unsigned t1 = (unsigned)__shfl((int)pk0[1][j2 & 1], srcLane);
      breg0[blk][j2] = (lg < 2) ? t0 : t1;
      unsigned u0 = (unsigned)__shfl((int)pk1[0][j2 & 1], srcLane);
      unsigned u1 = (unsigned)__shfl((int)pk1[1][j2 & 1], srcLane);
      breg1[blk][j2] = (lg < 2) ? u0 : u1;
    }
  }
  sum0 += __shfl_xor(sum0, 16);
  sum0 += __shfl_xor(sum0, 32);
  sum1 += __shfl_xor(sum1, 16);
  sum1 += __shfl_xor(sum1, 32);
  const float inv0 = 1.f / sum0, inv1 = 1.f / sum1;

  const ushort* vbase = Vt + ((size_t)(bh * kF + f) * kD + lr) * kPpad + lg * 8;
  f32x4 o0[4] = {}, o1[4] = {};
#pragma unroll
  for (int nt2 = 0; nt2 < 4; ++nt2) {
    const ushort* vb = vbase + (size_t)nt2 * 16 * kPpad;
#pragma unroll
    for (int blk = 0; blk < 7; ++blk) {
      bf16x8 av = *(const bf16x8*)(vb + blk * 32);
      bf16x8 pb0 = __builtin_bit_cast(bf16x8, breg0[blk]);
      bf16x8 pb1 = __builtin_bit_cast(bf16x8, breg1[blk]);
      o0[nt2] = __builtin_amdgcn_mfma_f32_16x16x32_bf16(av, pb0, o0[nt2], 0, 0, 0);
      o1[nt2] = __builtin_amdgcn_mfma_f32_16x16x32_bf16(av, pb1, o1[nt2], 0, 0, 0);
    }
  }

  const int b = bh / kH, h = bh % kH;
  const size_t base0 =
      ((size_t)(b * kS + q0 + lr) * kF + f) * kC + h * kD + lg * 4;
#pragma unroll
  for (int nt2 = 0; nt2 < 4; ++nt2) {
    ushort4 v0, v1;
    v0.x = f2bf(o0[nt2][0] * inv0);
    v0.y = f2bf(o0[nt2][1] * inv0);
    v0.z = f2bf(o0[nt2][2] * inv0);
    v0.w = f2bf(o0[nt2][3] * inv0);
    *(ushort4*)(x4b + base0 + nt2 * 16) = v0;
    v1.x = f2bf(o1[nt2][0] * inv1);
    v1.y = f2bf(o1[nt2][1] * inv1);
    v1.z = f2bf(o1[nt2][2] * inv1);
    v1.w = f2bf(o1[nt2][3] * inv1);
    *(ushort4*)(x4b + base0 + (size_t)16 * kF * kC + nt2 * 16) = v1;
  }
}

// ---------- cls attention, 4-phase parallel (bf16 qkv) ----------
__global__ __launch_bounds__(256) void cls_logits_k(const ushort* __restrict__ qkvb,
                                                    float* __restrict__ logits) {
  const int chunk = blockIdx.x, bh = blockIdx.y;
  const int b = bh / kH, h = bh % kH;
  const int g = threadIdx.x & 15, row = threadIdx.x >> 4;
  const size_t base = (size_t)b * kN * k3C;
  const ushort* qp = qkvb + base + h * kD + g * 4;
  const float q0 = bf2f(qp[0]) * kScale, q1 = bf2f(qp[1]) * kScale;
  const float q2 = bf2f(qp[2]) * kScale, q3 = bf2f(qp[3]) * kScale;
#pragma unroll
  for (int i = 0; i < 16; ++i) {
    const int n = chunk * 256 + i * 16 + row;
    if (n < kN) {
      ushort4 kv =
          *(const ushort4*)(qkvb + base + (size_t)n * k3C + kC + h * kD + g * 4);
      float p = q0 * bf2f(kv.x) + q1 * bf2f(kv.y) + q2 * bf2f(kv.z) +
                q3 * bf2f(kv.w);
#pragma unroll
      for (int o = 8; o; o >>= 1) p += __shfl_xor(p, o, 16);
      if (g == 0) logits[bh * kLpad + n] = p;
    }
  }
}

__global__ __launch_bounds__(256) void cls_softmax_k(const float* __restrict__ logits,
                                                     float* __restrict__ pbuf) {
  __shared__ float red[8];
  const int bh = blockIdx.x, tid = threadIdx.x;
  float m = -1e30f;
  for (int n = tid; n < kN; n += 256) m = fmaxf(m, logits[bh * kLpad + n]);
#pragma unroll
  for (int o = 32; o; o >>= 1) m = fmaxf(m, __shfl_xor(m, o));
  if ((tid & 63) == 0) red[tid >> 6] = m;
  __syncthreads();
  m = fmaxf(fmaxf(red[0], red[1]), fmaxf(red[2], red[3]));
  float sum = 0.f;
  for (int n = tid; n < kN; n += 256) sum += __expf(logits[bh * kLpad + n] - m);
#pragma unroll
  for (int o = 32; o; o >>= 1) sum += __shfl_xor(sum, o);
  if ((tid & 63) == 0) red[4 + (tid >> 6)] = sum;
  __syncthreads();
  const float inv = 1.f / (red[4] + red[5] + red[6] + red[7]);
  for (int n = tid; n < kN; n += 256)
    pbuf[bh * kLpad + n] = __expf(logits[bh * kLpad + n] - m) * inv;
}

__global__ __launch_bounds__(256) void cls_pv_k(const ushort* __restrict__ qkvb,
                                                const float* __restrict__ pbuf,
                                                float* __restrict__ partial) {
  __shared__ float pb[256];
  const int chunk = blockIdx.x, bh = blockIdx.y;
  const int b = bh / kH, h = bh % kH;
  const int j = threadIdx.x & 63, part = threadIdx.x >> 6;
  const size_t base = (size_t)b * kN * k3C + 2 * kC + h * kD + j;
  float acc = 0.f;
#pragma unroll 4
  for (int i = 0; i < 64; ++i) {
    const int n = chunk * 256 + i * 4 + part;
    if (n < kN)
      acc = fmaf(pbuf[bh * kLpad + n], bf2f(qkvb[base + (size_t)n * k3C]), acc);
  }
  pb[threadIdx.x] = acc;
  __syncthreads();
  if (part == 0)
    partial[((size_t)bh * 7 + chunk) * kD + j] =
        pb[j] + pb[64 + j] + pb[128 + j] + pb[192 + j];
}

__global__ void cls_red_k(const float* __restrict__ partial,
                          ushort* __restrict__ xin_b) {
  const int bh = blockIdx.x, j = threadIdx.x;
  const int b = bh / kH, h = bh % kH;
  float s = 0.f;
#pragma unroll
  for (int c = 0; c < 7; ++c) s += partial[((size_t)bh * 7 + c) * kD + j];
  xin_b[(size_t)(b * kN) * kC + h * kD + j] = f2bf(s);
}

// ---------- xd gather (bf16 -> bf16) ----------
__global__ void xd_gather_k(const ushort* __restrict__ x4b,
                            ushort* __restrict__ xd_b) {
  const int idx = blockIdx.x * 256 + threadIdx.x;
  const int total = kB * kS * (kC / 8);
  if (idx >= total) return;
  const int row = idx / (kC / 8);
  const int cg = idx - row * (kC / 8);
  const int b = row / kS, s = row - b * kS;
  const int fq = s / kP;
  ((ulonglong2*)xd_b)[(size_t)row * (kC / 8) + cg] =
      ((const ulonglong2*)x4b)[((size_t)(b * kS + s) * kF + fq) * (kC / 8) + cg];
}

// ---------- fused temporal attention: one block per (b,s) ----------
__global__ __launch_bounds__(256) void attn2_fused(
    const ushort* __restrict__ x4b, const ushort* __restrict__ w2b,
    ushort* __restrict__ xin_b, float* __restrict__ attn2out) {
  __shared__ __align__(16) ushort x4s[kF * kC];   // 12 KB
  __shared__ __align__(16) ushort w2s[kH * kC];   // 18 KB
  const int bs = blockIdx.x;
  const int b = bs / kS, s = bs - b * kS;
  const int tid = threadIdx.x;
  {
    const ulonglong2* src = (const ulonglong2*)(x4b + (size_t)bs * kF * kC);
    ulonglong2* dst = (ulonglong2*)x4s;
    for (int i = tid; i < kF * kC / 8; i += 256) dst[i] = src[i];
    const ulonglong2* srcw = (const ulonglong2*)(w2b + (size_t)bs * kH * kC);
    ulonglong2* dstw = (ulonglong2*)w2s;
    for (int i = tid; i < kH * kC / 8; i += 256) dstw[i] = srcw[i];
  }
  __syncthreads();
  const int w = tid >> 6, lane = tid & 63;
#pragma unroll
  for (int hh = 0; hh < 3; ++hh) {
    const int h = w * 3 + hh;
    float part[kF] = {};
#pragma unroll
    for (int i = 0; i < 3; ++i) {
      const int c = lane * 4 + i * 256;
      ushort4 wv = *(const ushort4*)&w2s[h * kC + c];
      const float w0 = bf2f(wv.x), w1 = bf2f(wv.y);
      const float w2v = bf2f(wv.z), w3 = bf2f(wv.w);
#pragma unroll
      for (int f = 0; f < kF; ++f) {
        ushort4 xv = *(const ushort4*)&x4s[f * kC + c];
        part[f] += bf2f(xv.x) * w0 + bf2f(xv.y) * w1 + bf2f(xv.z) * w2v +
                   bf2f(xv.w) * w3;
      }
    }
    float l[kF];
#pragma unroll
    for (int f = 0; f < kF; ++f) {
      float p = part[f];
#pragma unroll
      for (int o = 32; o; o >>= 1) p += __shfl_xor(p, o);
      l[f] = p;
    }
    float m = l[0];
#pragma unroll
    for (int f = 1; f < kF; ++f) m = fmaxf(m, l[f]);
    float sum = 0.f;
#pragma unroll
    for (int f = 0; f < kF; ++f) {
      l[f] = __expf(l[f] - m);
      sum += l[f];
    }
    const float inv = 1.f / sum;
    float pv = 0.f;
#pragma unroll
    for (int f = 0; f < kF; ++f) pv = (lane == f) ? l[f] : pv;
    if (lane < kF)
      attn2out[((size_t)(b * kH + h) * kS + s) * kF + lane] = pv * inv;
    float o = 0.f;
#pragma unroll
    for (int f = 0; f < kF; ++f)
      o = fmaf(l[f] * inv, bf2f(x4s[f * kC + h * kD + lane]), o);
    xin_b[(size_t)(b * kN + 1 + s) * kC + h * kD + lane] = f2bf(o);
  }
}

extern "C" void kernel_launch(void* const* d_in, const int* in_sizes, int n_in,
                              void* d_out, int out_size, void* d_ws,
                              size_t ws_size, hipStream_t stream) {
  const float* x = (const float*)d_in[0];
  const float* Wqkv = (const float*)d_in[1];
  const float* Wq = (const float*)d_in[2];
  const float* Wkv = (const float*)d_in[3];
  const float* Wproj = (const float*)d_in[4];
  const float* bproj = (const float*)d_in[5];

  char* p = (char*)d_ws;
  ushort* qkvb = (ushort*)p;         p += (size_t)3138 * 2304 * 2;
  ushort* w2b = (ushort*)p;          p += (size_t)kBS * kH * kC * 2;
  ushort* q2b = (ushort*)p;          p += (size_t)kBS * kC * 2;
  ushort* x4b = (ushort*)p;          p += (size_t)25088 * 768 * 2;
  ushort* xin_b = (ushort*)p;        p += (size_t)3138 * 768 * 2;
  ushort* xd_b = (ushort*)p;         p += (size_t)kBS * 768 * 2;
  ushort* xb = (ushort*)p;           p += (size_t)3138 * 768 * 2;
  ushort* Wqkv_t = (ushort*)p;       p += (size_t)2304 * 768 * 2;
  ushort* Wq_t = (ushort*)p;         p += (size_t)768 * 768 * 2;
  ushort* Wkvb = (ushort*)p;         p += (size_t)768 * 768 * 2;
  ushort* Wproj_t = (ushort*)p;      p += (size_t)768 * 768 * 2;
  ushort* Qb = (ushort*)p;           p += (size_t)kBH * kS * kD * 2;
  ushort* Kb = (ushort*)p;           p += ((size_t)kBH * kS + 16) * kD * 2;
  ushort* Vt = (ushort*)p;           p += (size_t)kBH * kF * kD * kPpad * 2;
  float* clsL = (float*)p;           p += (size_t)kBH * kLpad * 4;
  float* clsP = (float*)p;           p += (size_t)kBH * kLpad * 4;
  float* clsPart = (float*)p;

  float* out = (float*)d_out;
  float* attn2 = out + (size_t)kB * kN * kC;

  // 0. packs (kScale folded exactly into Wq_t: 0.125 is a power of 2)
  pack_x_k<<<(3138 * 768 / 4 + 255) / 256, 256, 0, stream>>>(x, xb, 3138 * 768 / 4);
  pack_wt_k<<<dim3(72, 24), 256, 0, stream>>>(Wqkv, Wqkv_t, 2304, 1.f);
  pack_wt_k<<<dim3(24, 24), 256, 0, stream>>>(Wq, Wq_t, 768, kScale);
  pack_wkv_k<<<(768 * 192 + 255) / 256, 256, 0, stream>>>(Wkv, Wkvb);
  pack_wt_k<<<dim3(24, 24), 256, 0, stream>>>(Wproj, Wproj_t, 768, 1.f);
  // 1. qkv = x @ Wqkv (bf16 out — attention packs were rounding to bf16 anyway)
  gemm_bf16<ushort><<<18 * 25, 256, 0, stream>>>(xb, Wqkv_t, nullptr, qkvb,
                                                 3138, 2304, 768, 18);
  // 2. pack attention operands (reads bf16; Q-scale exact)
  pack_qk_k<<<(kBH * kS * 8 + 255) / 256, 256, 0, stream>>>(qkvb, Qb, Kb);
  pack_vt_k<<<(kBH * kF * kD * kPpad + 255) / 256, 256, 0, stream>>>(qkvb, Vt);
  // 3. cls attention (4-phase)
  cls_logits_k<<<dim3(7, 24), 256, 0, stream>>>(qkvb, clsL);
  cls_softmax_k<<<24, 256, 0, stream>>>(clsL, clsP);
  cls_pv_k<<<dim3(7, 24), 256, 0, stream>>>(qkvb, clsP, clsPart);
  cls_red_k<<<24, 64, 0, stream>>>(clsPart, xin_b);
  // 4. spatial attention -> x4b (round-7 proven kernel)
  sp_attn_mfma<<<dim3(192, 13), 256, 0, stream>>>(Qb, Kb, Vt, x4b);
  // 5. xd gather
  xd_gather_k<<<(kB * kS * (kC / 8) + 255) / 256, 256, 0, stream>>>(x4b, xd_b);
  // 6. q2 = xd @ (Wq * scale)  (bf16 out, pre-scaled)
  gemm_bf16<ushort><<<6 * 25, 256, 0, stream>>>(xd_b, Wq_t, nullptr, q2b, kBS,
                                                768, 768, 6);
  // 7. w2[bs,h,:] = Wkv_h^T @ q2[bs,h,:]
  w2_gemm<<<1800, 256, 0, stream>>>(q2b, Wkvb, w2b);
  // 8. fused temporal attention
  attn2_fused<<<kBS, 256, 0, stream>>>(x4b, w2b, xin_b, attn2);
  // 9. out = xin @ Wproj + bproj (fp32 out)
  gemm_bf16<float><<<6 * 25, 256, 0, stream>>>(xin_b, Wproj_t, bproj, out, 3138,
                                               768, 768, 6);
}